// Round 2
// baseline (7285.586 us; speedup 1.0000x reference)
//
#include <hip/hip_runtime.h>
#include <math.h>

#define TDIM 16384
#define DDIM 1024
#define CDIM 256
#define KDIM 8192
#define KSPLIT 8

// ---- workspace layout (float offsets) ----
static const size_t OFF_WIN  = 0;                                   // 256x1024
static const size_t OFF_WOUT = OFF_WIN  + (size_t)CDIM * DDIM;      // 1024x256
static const size_t OFF_CBU  = OFF_WOUT + (size_t)DDIM * CDIM;      // 8192x256
static const size_t OFF_C2   = OFF_CBU  + (size_t)KDIM * CDIM;      // 8192
static const size_t OFF_ZE   = OFF_C2   + (size_t)KDIM;             // 256x16384
static const size_t OFF_INV  = OFF_ZE   + (size_t)CDIM * TDIM;      // 16384
static const size_t OFF_ZQ   = OFF_INV  + (size_t)TDIM;             // 256x16384 ([c][t])
static const size_t OFF_PV   = OFF_ZQ   + (size_t)CDIM * TDIM;      // 8x16384
static const size_t OFF_PI   = OFF_PV   + (size_t)KSPLIT * TDIM;    // 8x16384 (int)
static const size_t OFF_IDX  = OFF_PI   + (size_t)KSPLIT * TDIM;    // 16384 (int)

// ---------------------------------------------------------------------------
// Row-wise L2 normalize: w[row] = (g?g[row]:1) * v[row] / norm(v[row])
// optional clip(norm, 1e-12); optional c2[row] = sum(w[row]^2) of ROUNDED w.
// ---------------------------------------------------------------------------
__global__ __launch_bounds__(256) void rownorm_kernel(
    const float* __restrict__ v, const float* __restrict__ g,
    float* __restrict__ w, float* __restrict__ c2, int ncols, int clip) {
  __shared__ float red[256];
  int row = blockIdx.x;
  const float* vr = v + (size_t)row * ncols;
  float* wr = w + (size_t)row * ncols;
  float s = 0.f;
  for (int j = threadIdx.x; j < ncols; j += 256) { float x = vr[j]; s += x * x; }
  red[threadIdx.x] = s;
  __syncthreads();
  for (int off = 128; off > 0; off >>= 1) {
    if (threadIdx.x < off) red[threadIdx.x] += red[threadIdx.x + off];
    __syncthreads();
  }
  float norm = sqrtf(red[0]);
  if (clip) norm = fmaxf(norm, 1e-12f);
  float scale = (g ? g[row] : 1.0f) / norm;
  float s2 = 0.f;
  for (int j = threadIdx.x; j < ncols; j += 256) {
    float y = vr[j] * scale;
    wr[j] = y;
    s2 += y * y;
  }
  if (c2) {
    __syncthreads();
    red[threadIdx.x] = s2;
    __syncthreads();
    for (int off = 128; off > 0; off >>= 1) {
      if (threadIdx.x < off) red[threadIdx.x] += red[threadIdx.x + off];
      __syncthreads();
    }
    if (threadIdx.x == 0) c2[row] = red[0];
  }
}

// ---------------------------------------------------------------------------
// Unified fp32 GEMM: C(M x TDIM) = A(M x K) @ B(K x TDIM) + bias[m]
// BM=128 BN=128 BK=8, 256 thr, 8x8 microtile with split (+64) addressing:
// rows tm_lo+{0..3}, tm_lo+64+{0..3}; cols tn_lo+{0..3}, tn_lo+64+{0..3}.
// Conflict-free fragment reads (16 consecutive quads/wave), b128 Bs stores.
// ---------------------------------------------------------------------------
__global__ __launch_bounds__(256) void gemm_bias(
    const float* __restrict__ A, const float* __restrict__ B,
    const float* __restrict__ bias, float* __restrict__ C, int K) {
  __shared__ float As[8][128];
  __shared__ float Bs[8][128];
  const int N = TDIM;
  int m0 = blockIdx.y * 128;
  int n0 = blockIdx.x * 128;
  int tid = threadIdx.x;
  int tm_lo = (tid >> 4) * 4;
  int tn_lo = (tid & 15) * 4;
  int a_r = tid >> 1, a_c = (tid & 1) * 4;      // A tile loader
  int b_r = tid >> 5, b_c = (tid & 31) * 4;     // B tile loader
  float acc[8][8] = {};
  float4 av = *(const float4*)&A[(size_t)(m0 + a_r) * K + a_c];
  float4 bw = *(const float4*)&B[(size_t)b_r * N + n0 + b_c];
  for (int k0 = 0; k0 < K; k0 += 8) {
    __syncthreads();
    As[a_c + 0][a_r] = av.x; As[a_c + 1][a_r] = av.y;   // 2-way scatter (free)
    As[a_c + 2][a_r] = av.z; As[a_c + 3][a_r] = av.w;
    *(float4*)&Bs[b_r][b_c] = bw;                        // b128, conflict-free
    __syncthreads();
    if (k0 + 8 < K) {
      av = *(const float4*)&A[(size_t)(m0 + a_r) * K + k0 + 8 + a_c];
      bw = *(const float4*)&B[(size_t)(k0 + 8 + b_r) * N + n0 + b_c];
    }
#pragma unroll
    for (int kk = 0; kk < 8; kk++) {
      float a[8], b[8];
      *(float4*)&a[0] = *(const float4*)&As[kk][tm_lo];
      *(float4*)&a[4] = *(const float4*)&As[kk][tm_lo + 64];
      *(float4*)&b[0] = *(const float4*)&Bs[kk][tn_lo];
      *(float4*)&b[4] = *(const float4*)&Bs[kk][tn_lo + 64];
#pragma unroll
      for (int i = 0; i < 8; i++)
#pragma unroll
        for (int j = 0; j < 8; j++) acc[i][j] += a[i] * b[j];
    }
  }
#pragma unroll
  for (int i = 0; i < 8; i++) {
    int row = (i < 4) ? (tm_lo + i) : (tm_lo + 64 + i - 4);
    float bb = bias[m0 + row];
    float4 o0, o1;
    o0.x = acc[i][0] + bb; o0.y = acc[i][1] + bb;
    o0.z = acc[i][2] + bb; o0.w = acc[i][3] + bb;
    o1.x = acc[i][4] + bb; o1.y = acc[i][5] + bb;
    o1.z = acc[i][6] + bb; o1.w = acc[i][7] + bb;
    *(float4*)&C[(size_t)(m0 + row) * N + n0 + tn_lo] = o0;
    *(float4*)&C[(size_t)(m0 + row) * N + n0 + tn_lo + 64] = o1;
  }
}

// ---------------------------------------------------------------------------
// column norms of z_e (CD x T): inv[t] = 1/clip(||z_e[:,t]||, 1e-12)
// ---------------------------------------------------------------------------
__global__ __launch_bounds__(256) void colnorm_kernel(
    const float* __restrict__ ze, float* __restrict__ inv) {
  __shared__ float red[4][64];
  int tl = threadIdx.x & 63, part = threadIdx.x >> 6;
  int t = blockIdx.x * 64 + tl;
  float s = 0.f;
  for (int c = part * 64; c < part * 64 + 64; c++) {
    float x = ze[(size_t)c * TDIM + t];
    s += x * x;
  }
  red[part][tl] = s;
  __syncthreads();
  if (part == 0) {
    float tot = red[0][tl] + red[1][tl] + red[2][tl] + red[3][tl];
    inv[t] = 1.0f / fmaxf(sqrtf(tot), 1e-12f);
  }
}

// ---------------------------------------------------------------------------
// dist + argmin: t-tile (128) x k-range (KDIM/KSPLIT=1024), running argmin of
//   s = c2[k] - 2 * dot(enc[:,t], cbu[k]),  enc = z_e[:,t] * inv[t]
// Split 8x8 microtile; b128 As stores; conflict-free fragment reads.
// ---------------------------------------------------------------------------
__global__ __launch_bounds__(256, 4) void dist_argmin(
    const float* __restrict__ ze, const float* __restrict__ inv,
    const float* __restrict__ cbu, const float* __restrict__ c2,
    float* __restrict__ pv, int* __restrict__ pi) {
  __shared__ float As[8][128];
  __shared__ float Bs[8][128];
  __shared__ float rv[128 * 17];
  __shared__ int   ri[128 * 17];
  int t0 = blockIdx.x * 128;
  int kbeg = blockIdx.y * (KDIM / KSPLIT);
  int tid = threadIdx.x;
  int tm_lo = (tid >> 4) * 4;
  int tn_lo = (tid & 15) * 4;
  int ar = tid >> 5, ac4 = (tid & 31) * 4;   // A tile: [8 c][128 t]
  int br = tid >> 1, bc4 = (tid & 1) * 4;    // B tile: [128 k][8 c] -> Bs[c][k]
  float4 iv = *(const float4*)&inv[t0 + ac4];  // loop-invariant
  float bv[8]; int bi[8];
#pragma unroll
  for (int i = 0; i < 8; i++) { bv[i] = INFINITY; bi[i] = 0x7fffffff; }

  for (int kc = 0; kc < KDIM / KSPLIT; kc += 128) {
    int k0 = kbeg + kc;
    float acc[8][8] = {};
    float4 av = *(const float4*)&ze[(size_t)ar * TDIM + t0 + ac4];
    float4 bw = *(const float4*)&cbu[(size_t)(k0 + br) * CDIM + bc4];
    for (int c0 = 0; c0 < CDIM; c0 += 8) {
      __syncthreads();
      float4 asv;
      asv.x = av.x * iv.x; asv.y = av.y * iv.y;
      asv.z = av.z * iv.z; asv.w = av.w * iv.w;
      *(float4*)&As[ar][ac4] = asv;                      // b128, conflict-free
      Bs[bc4 + 0][br] = bw.x; Bs[bc4 + 1][br] = bw.y;    // 2-way scatter (free)
      Bs[bc4 + 2][br] = bw.z; Bs[bc4 + 3][br] = bw.w;
      __syncthreads();
      if (c0 + 8 < CDIM) {
        av = *(const float4*)&ze[(size_t)(c0 + 8 + ar) * TDIM + t0 + ac4];
        bw = *(const float4*)&cbu[(size_t)(k0 + br) * CDIM + c0 + 8 + bc4];
      }
#pragma unroll
      for (int kk = 0; kk < 8; kk++) {
        float a[8], b[8];
        *(float4*)&a[0] = *(const float4*)&As[kk][tm_lo];
        *(float4*)&a[4] = *(const float4*)&As[kk][tm_lo + 64];
        *(float4*)&b[0] = *(const float4*)&Bs[kk][tn_lo];
        *(float4*)&b[4] = *(const float4*)&Bs[kk][tn_lo + 64];
#pragma unroll
        for (int i = 0; i < 8; i++)
#pragma unroll
          for (int j = 0; j < 8; j++) acc[i][j] += a[i] * b[j];
      }
    }
    float c2v[8];
    *(float4*)&c2v[0] = *(const float4*)&c2[k0 + tn_lo];
    *(float4*)&c2v[4] = *(const float4*)&c2[k0 + tn_lo + 64];
#pragma unroll
    for (int i = 0; i < 8; i++)
#pragma unroll
      for (int j = 0; j < 8; j++) {
        float s = c2v[j] - 2.0f * acc[i][j];
        int kidx = k0 + ((j < 4) ? (tn_lo + j) : (tn_lo + 64 + j - 4));
        // j ascending => kidx ascending within thread; strict <: earliest k wins
        if (s < bv[i]) { bv[i] = s; bi[i] = kidx; }
      }
  }

  // cross-thread (tx) reduce per t row; tie-break: smaller k wins
  int tx = tid & 15;
#pragma unroll
  for (int i = 0; i < 8; i++) {
    int row = (i < 4) ? (tm_lo + i) : (tm_lo + 64 + i - 4);
    rv[row * 17 + tx] = bv[i];
    ri[row * 17 + tx] = bi[i];
  }
  __syncthreads();
  if (tid < 128) {
    float fbv = INFINITY; int fbi = 0x7fffffff;
    for (int j = 0; j < 16; j++) {
      float v = rv[tid * 17 + j];
      int ii = ri[tid * 17 + j];
      if (v < fbv || (v == fbv && ii < fbi)) { fbv = v; fbi = ii; }
    }
    pv[(size_t)blockIdx.y * TDIM + t0 + tid] = fbv;
    pi[(size_t)blockIdx.y * TDIM + t0 + tid] = fbi;
  }
}

// ---------------------------------------------------------------------------
// merge k-splits; emit int idx (for gather) and float idx (output 1)
// ---------------------------------------------------------------------------
__global__ __launch_bounds__(256) void merge_argmin(
    const float* __restrict__ pv, const int* __restrict__ pi,
    int* __restrict__ idx, float* __restrict__ idxf) {
  int t = blockIdx.x * 256 + threadIdx.x;
  float bv = INFINITY; int bi = 0x7fffffff;
  for (int s = 0; s < KSPLIT; s++) {
    float v = pv[(size_t)s * TDIM + t];
    int ii = pi[(size_t)s * TDIM + t];
    if (v < bv || (v == bv && ii < bi)) { bv = v; bi = ii; }
  }
  idx[t] = bi;
  idxf[t] = (float)bi;
}

// ---------------------------------------------------------------------------
// STE gather into [CD][T] layout: zq[c][t] = ze[c][t] + (cb[idx[t]][c]-ze[c][t])
// lanes = consecutive t (coalesced ze read / zq write); cb rows via L2.
// ---------------------------------------------------------------------------
__global__ __launch_bounds__(256) void gather_zq(
    const int* __restrict__ idx, const float* __restrict__ cb,
    const float* __restrict__ ze, float* __restrict__ zq) {
  int tl = threadIdx.x & 63, cgrp = threadIdx.x >> 6;
  int t = blockIdx.x * 64 + tl;
  int k = idx[t];
  const float* cbr = cb + (size_t)k * CDIM;
  for (int c = cgrp * 64; c < cgrp * 64 + 64; c++) {
    float cbv = cbr[c];
    float zev = ze[(size_t)c * TDIM + t];
    zq[(size_t)c * TDIM + t] = zev + (cbv - zev);
  }
}

extern "C" void kernel_launch(void* const* d_in, const int* in_sizes, int n_in,
                              void* d_out, int out_size, void* d_ws, size_t ws_size,
                              hipStream_t stream) {
  const float* z     = (const float*)d_in[0];
  const float* in_v  = (const float*)d_in[1];
  const float* in_g  = (const float*)d_in[2];
  const float* in_b  = (const float*)d_in[3];
  const float* out_v = (const float*)d_in[4];
  const float* out_g = (const float*)d_in[5];
  const float* out_b = (const float*)d_in[6];
  const float* cb    = (const float*)d_in[7];

  float* ws    = (float*)d_ws;
  float* W_in  = ws + OFF_WIN;
  float* W_out = ws + OFF_WOUT;
  float* cbu   = ws + OFF_CBU;
  float* c2    = ws + OFF_C2;
  float* z_e   = ws + OFF_ZE;
  float* invn  = ws + OFF_INV;
  float* zq    = ws + OFF_ZQ;
  float* pv    = ws + OFF_PV;
  int*   pi    = (int*)(ws + OFF_PI);
  int*   idxw  = (int*)(ws + OFF_IDX);

  float* outp = (float*)d_out;                 // (1024 x 16384) fp32
  float* idxf = outp + (size_t)DDIM * TDIM;    // indices as float32

  // weight-norm + codebook normalize
  rownorm_kernel<<<CDIM, 256, 0, stream>>>(in_v, in_g, W_in, nullptr, DDIM, 0);
  rownorm_kernel<<<DDIM, 256, 0, stream>>>(out_v, out_g, W_out, nullptr, CDIM, 0);
  rownorm_kernel<<<KDIM, 256, 0, stream>>>(cb, nullptr, cbu, c2, CDIM, 1);

  // z_e = W_in @ z + in_b   (M=256, K=1024)
  gemm_bias<<<dim3(TDIM / 128, CDIM / 128), 256, 0, stream>>>(W_in, z, in_b, z_e, DDIM);

  // inv column norms
  colnorm_kernel<<<TDIM / 64, 256, 0, stream>>>(z_e, invn);

  // nearest-codebook argmin (k-split x8)
  dist_argmin<<<dim3(TDIM / 128, KSPLIT), 256, 0, stream>>>(z_e, invn, cbu, c2, pv, pi);
  merge_argmin<<<TDIM / 256, 256, 0, stream>>>(pv, pi, idxw, idxf);

  // STE gather into [CD][T]
  gather_zq<<<TDIM / 64, 256, 0, stream>>>(idxw, cb, z_e, zq);

  // out = W_out @ z_q + out_b   (M=1024, K=256)
  gemm_bias<<<dim3(TDIM / 128, DDIM / 128), 256, 0, stream>>>(W_out, zq, out_b, outp, CDIM);
}

// Round 3
// 1174.076 us; speedup vs baseline: 6.2054x; 6.2054x over previous
//
#include <hip/hip_runtime.h>
#include <math.h>

#define TDIM 16384
#define DDIM 1024
#define CDIM 256
#define KDIM 8192
#define KSPLIT 8

// ---- workspace layout (float offsets) ----
static const size_t OFF_WIN  = 0;                                   // 256x1024
static const size_t OFF_WOUT = OFF_WIN  + (size_t)CDIM * DDIM;      // 1024x256
static const size_t OFF_CBU  = OFF_WOUT + (size_t)DDIM * CDIM;      // 8192x256
static const size_t OFF_C2   = OFF_CBU  + (size_t)KDIM * CDIM;      // 8192
static const size_t OFF_ZE   = OFF_C2   + (size_t)KDIM;             // 256x16384
static const size_t OFF_INV  = OFF_ZE   + (size_t)CDIM * TDIM;      // 16384
static const size_t OFF_ZQ   = OFF_INV  + (size_t)TDIM;             // 256x16384 ([c][t])
static const size_t OFF_PV   = OFF_ZQ   + (size_t)CDIM * TDIM;      // 8x16384
static const size_t OFF_PI   = OFF_PV   + (size_t)KSPLIT * TDIM;    // 8x16384 (int)
static const size_t OFF_IDX  = OFF_PI   + (size_t)KSPLIT * TDIM;    // 16384 (int)

// ---------------------------------------------------------------------------
// Row-wise L2 normalize: w[row] = (g?g[row]:1) * v[row] / norm(v[row])
// optional clip(norm, 1e-12); optional c2[row] = sum(w[row]^2) of ROUNDED w.
// ---------------------------------------------------------------------------
__global__ __launch_bounds__(256) void rownorm_kernel(
    const float* __restrict__ v, const float* __restrict__ g,
    float* __restrict__ w, float* __restrict__ c2, int ncols, int clip) {
  __shared__ float red[256];
  int row = blockIdx.x;
  const float* vr = v + (size_t)row * ncols;
  float* wr = w + (size_t)row * ncols;
  float s = 0.f;
  for (int j = threadIdx.x; j < ncols; j += 256) { float x = vr[j]; s += x * x; }
  red[threadIdx.x] = s;
  __syncthreads();
  for (int off = 128; off > 0; off >>= 1) {
    if (threadIdx.x < off) red[threadIdx.x] += red[threadIdx.x + off];
    __syncthreads();
  }
  float norm = sqrtf(red[0]);
  if (clip) norm = fmaxf(norm, 1e-12f);
  float scale = (g ? g[row] : 1.0f) / norm;
  float s2 = 0.f;
  for (int j = threadIdx.x; j < ncols; j += 256) {
    float y = vr[j] * scale;
    wr[j] = y;
    s2 += y * y;
  }
  if (c2) {
    __syncthreads();
    red[threadIdx.x] = s2;
    __syncthreads();
    for (int off = 128; off > 0; off >>= 1) {
      if (threadIdx.x < off) red[threadIdx.x] += red[threadIdx.x + off];
      __syncthreads();
    }
    if (threadIdx.x == 0) c2[row] = red[0];
  }
}

// ---------------------------------------------------------------------------
// Unified fp32 GEMM: C(M x TDIM) = A(M x K) @ B(K x TDIM) + bias[m]
// BM=128 BN=128 BK=8, 256 thr, 8x8 microtile with split (+64) addressing.
// NOTE: no min-waves clause in __launch_bounds__ — forcing 4 waves/EU caps
// VGPR at 64 and spills the 64-float accumulator to scratch (R2: 36 GB/launch
// of scratch traffic, 7.9x regression). Let the allocator pick (~120 VGPR).
// ---------------------------------------------------------------------------
__global__ __launch_bounds__(256) void gemm_bias(
    const float* __restrict__ A, const float* __restrict__ B,
    const float* __restrict__ bias, float* __restrict__ C, int K) {
  __shared__ float As[8][128];
  __shared__ float Bs[8][128];
  const int N = TDIM;
  int m0 = blockIdx.y * 128;
  int n0 = blockIdx.x * 128;
  int tid = threadIdx.x;
  int tm_lo = (tid >> 4) * 4;
  int tn_lo = (tid & 15) * 4;
  int a_r = tid >> 1, a_c = (tid & 1) * 4;      // A tile loader
  int b_r = tid >> 5, b_c = (tid & 31) * 4;     // B tile loader
  float acc[8][8] = {};
  float4 av = *(const float4*)&A[(size_t)(m0 + a_r) * K + a_c];
  float4 bw = *(const float4*)&B[(size_t)b_r * N + n0 + b_c];
  for (int k0 = 0; k0 < K; k0 += 8) {
    __syncthreads();
    As[a_c + 0][a_r] = av.x; As[a_c + 1][a_r] = av.y;   // 2-way scatter (free)
    As[a_c + 2][a_r] = av.z; As[a_c + 3][a_r] = av.w;
    *(float4*)&Bs[b_r][b_c] = bw;                        // b128, conflict-free
    __syncthreads();
    if (k0 + 8 < K) {
      av = *(const float4*)&A[(size_t)(m0 + a_r) * K + k0 + 8 + a_c];
      bw = *(const float4*)&B[(size_t)(k0 + 8 + b_r) * N + n0 + b_c];
    }
#pragma unroll
    for (int kk = 0; kk < 8; kk++) {
      float a[8], b[8];
      *(float4*)&a[0] = *(const float4*)&As[kk][tm_lo];
      *(float4*)&a[4] = *(const float4*)&As[kk][tm_lo + 64];
      *(float4*)&b[0] = *(const float4*)&Bs[kk][tn_lo];
      *(float4*)&b[4] = *(const float4*)&Bs[kk][tn_lo + 64];
#pragma unroll
      for (int i = 0; i < 8; i++)
#pragma unroll
        for (int j = 0; j < 8; j++) acc[i][j] += a[i] * b[j];
    }
  }
#pragma unroll
  for (int i = 0; i < 8; i++) {
    int row = (i < 4) ? (tm_lo + i) : (tm_lo + 64 + i - 4);
    float bb = bias[m0 + row];
    float4 o0, o1;
    o0.x = acc[i][0] + bb; o0.y = acc[i][1] + bb;
    o0.z = acc[i][2] + bb; o0.w = acc[i][3] + bb;
    o1.x = acc[i][4] + bb; o1.y = acc[i][5] + bb;
    o1.z = acc[i][6] + bb; o1.w = acc[i][7] + bb;
    *(float4*)&C[(size_t)(m0 + row) * N + n0 + tn_lo] = o0;
    *(float4*)&C[(size_t)(m0 + row) * N + n0 + tn_lo + 64] = o1;
  }
}

// ---------------------------------------------------------------------------
// column norms of z_e (CD x T): inv[t] = 1/clip(||z_e[:,t]||, 1e-12)
// ---------------------------------------------------------------------------
__global__ __launch_bounds__(256) void colnorm_kernel(
    const float* __restrict__ ze, float* __restrict__ inv) {
  __shared__ float red[4][64];
  int tl = threadIdx.x & 63, part = threadIdx.x >> 6;
  int t = blockIdx.x * 64 + tl;
  float s = 0.f;
  for (int c = part * 64; c < part * 64 + 64; c++) {
    float x = ze[(size_t)c * TDIM + t];
    s += x * x;
  }
  red[part][tl] = s;
  __syncthreads();
  if (part == 0) {
    float tot = red[0][tl] + red[1][tl] + red[2][tl] + red[3][tl];
    inv[t] = 1.0f / fmaxf(sqrtf(tot), 1e-12f);
  }
}

// ---------------------------------------------------------------------------
// dist + argmin: t-tile (128) x k-range (KDIM/KSPLIT=1024), running argmin of
//   s = c2[k] - 2 * dot(enc[:,t], cbu[k]),  enc = z_e[:,t] * inv[t]
// Split 8x8 microtile; b128 As stores; conflict-free fragment reads.
// __launch_bounds__(256) ONLY — see gemm_bias note (R2 spill disaster).
// ---------------------------------------------------------------------------
__global__ __launch_bounds__(256) void dist_argmin(
    const float* __restrict__ ze, const float* __restrict__ inv,
    const float* __restrict__ cbu, const float* __restrict__ c2,
    float* __restrict__ pv, int* __restrict__ pi) {
  __shared__ float As[8][128];
  __shared__ float Bs[8][128];
  __shared__ float rv[128 * 17];
  __shared__ int   ri[128 * 17];
  int t0 = blockIdx.x * 128;
  int kbeg = blockIdx.y * (KDIM / KSPLIT);
  int tid = threadIdx.x;
  int tm_lo = (tid >> 4) * 4;
  int tn_lo = (tid & 15) * 4;
  int ar = tid >> 5, ac4 = (tid & 31) * 4;   // A tile: [8 c][128 t]
  int br = tid >> 1, bc4 = (tid & 1) * 4;    // B tile: [128 k][8 c] -> Bs[c][k]
  float4 iv = *(const float4*)&inv[t0 + ac4];  // loop-invariant
  float bv[8]; int bi[8];
#pragma unroll
  for (int i = 0; i < 8; i++) { bv[i] = INFINITY; bi[i] = 0x7fffffff; }

  for (int kc = 0; kc < KDIM / KSPLIT; kc += 128) {
    int k0 = kbeg + kc;
    float acc[8][8] = {};
    float4 av = *(const float4*)&ze[(size_t)ar * TDIM + t0 + ac4];
    float4 bw = *(const float4*)&cbu[(size_t)(k0 + br) * CDIM + bc4];
    for (int c0 = 0; c0 < CDIM; c0 += 8) {
      __syncthreads();
      float4 asv;
      asv.x = av.x * iv.x; asv.y = av.y * iv.y;
      asv.z = av.z * iv.z; asv.w = av.w * iv.w;
      *(float4*)&As[ar][ac4] = asv;                      // b128, conflict-free
      Bs[bc4 + 0][br] = bw.x; Bs[bc4 + 1][br] = bw.y;    // 2-way scatter (free)
      Bs[bc4 + 2][br] = bw.z; Bs[bc4 + 3][br] = bw.w;
      __syncthreads();
      if (c0 + 8 < CDIM) {
        av = *(const float4*)&ze[(size_t)(c0 + 8 + ar) * TDIM + t0 + ac4];
        bw = *(const float4*)&cbu[(size_t)(k0 + br) * CDIM + c0 + 8 + bc4];
      }
#pragma unroll
      for (int kk = 0; kk < 8; kk++) {
        float a[8], b[8];
        *(float4*)&a[0] = *(const float4*)&As[kk][tm_lo];
        *(float4*)&a[4] = *(const float4*)&As[kk][tm_lo + 64];
        *(float4*)&b[0] = *(const float4*)&Bs[kk][tn_lo];
        *(float4*)&b[4] = *(const float4*)&Bs[kk][tn_lo + 64];
#pragma unroll
        for (int i = 0; i < 8; i++)
#pragma unroll
          for (int j = 0; j < 8; j++) acc[i][j] += a[i] * b[j];
      }
    }
    float c2v[8];
    *(float4*)&c2v[0] = *(const float4*)&c2[k0 + tn_lo];
    *(float4*)&c2v[4] = *(const float4*)&c2[k0 + tn_lo + 64];
#pragma unroll
    for (int i = 0; i < 8; i++)
#pragma unroll
      for (int j = 0; j < 8; j++) {
        float s = c2v[j] - 2.0f * acc[i][j];
        int kidx = k0 + ((j < 4) ? (tn_lo + j) : (tn_lo + 64 + j - 4));
        // j ascending => kidx ascending within thread; strict <: earliest k wins
        if (s < bv[i]) { bv[i] = s; bi[i] = kidx; }
      }
  }

  // cross-thread (tx) reduce per t row; tie-break: smaller k wins
  int tx = tid & 15;
#pragma unroll
  for (int i = 0; i < 8; i++) {
    int row = (i < 4) ? (tm_lo + i) : (tm_lo + 64 + i - 4);
    rv[row * 17 + tx] = bv[i];
    ri[row * 17 + tx] = bi[i];
  }
  __syncthreads();
  if (tid < 128) {
    float fbv = INFINITY; int fbi = 0x7fffffff;
    for (int j = 0; j < 16; j++) {
      float v = rv[tid * 17 + j];
      int ii = ri[tid * 17 + j];
      if (v < fbv || (v == fbv && ii < fbi)) { fbv = v; fbi = ii; }
    }
    pv[(size_t)blockIdx.y * TDIM + t0 + tid] = fbv;
    pi[(size_t)blockIdx.y * TDIM + t0 + tid] = fbi;
  }
}

// ---------------------------------------------------------------------------
// merge k-splits; emit int idx (for gather) and float idx (output 1)
// ---------------------------------------------------------------------------
__global__ __launch_bounds__(256) void merge_argmin(
    const float* __restrict__ pv, const int* __restrict__ pi,
    int* __restrict__ idx, float* __restrict__ idxf) {
  int t = blockIdx.x * 256 + threadIdx.x;
  float bv = INFINITY; int bi = 0x7fffffff;
  for (int s = 0; s < KSPLIT; s++) {
    float v = pv[(size_t)s * TDIM + t];
    int ii = pi[(size_t)s * TDIM + t];
    if (v < bv || (v == bv && ii < bi)) { bv = v; bi = ii; }
  }
  idx[t] = bi;
  idxf[t] = (float)bi;
}

// ---------------------------------------------------------------------------
// STE gather into [CD][T] layout: zq[c][t] = ze[c][t] + (cb[idx[t]][c]-ze[c][t])
// lanes = consecutive t (coalesced ze read / zq write); cb rows via L2.
// ---------------------------------------------------------------------------
__global__ __launch_bounds__(256) void gather_zq(
    const int* __restrict__ idx, const float* __restrict__ cb,
    const float* __restrict__ ze, float* __restrict__ zq) {
  int tl = threadIdx.x & 63, cgrp = threadIdx.x >> 6;
  int t = blockIdx.x * 64 + tl;
  int k = idx[t];
  const float* cbr = cb + (size_t)k * CDIM;
  for (int c = cgrp * 64; c < cgrp * 64 + 64; c++) {
    float cbv = cbr[c];
    float zev = ze[(size_t)c * TDIM + t];
    zq[(size_t)c * TDIM + t] = zev + (cbv - zev);
  }
}

extern "C" void kernel_launch(void* const* d_in, const int* in_sizes, int n_in,
                              void* d_out, int out_size, void* d_ws, size_t ws_size,
                              hipStream_t stream) {
  const float* z     = (const float*)d_in[0];
  const float* in_v  = (const float*)d_in[1];
  const float* in_g  = (const float*)d_in[2];
  const float* in_b  = (const float*)d_in[3];
  const float* out_v = (const float*)d_in[4];
  const float* out_g = (const float*)d_in[5];
  const float* out_b = (const float*)d_in[6];
  const float* cb    = (const float*)d_in[7];

  float* ws    = (float*)d_ws;
  float* W_in  = ws + OFF_WIN;
  float* W_out = ws + OFF_WOUT;
  float* cbu   = ws + OFF_CBU;
  float* c2    = ws + OFF_C2;
  float* z_e   = ws + OFF_ZE;
  float* invn  = ws + OFF_INV;
  float* zq    = ws + OFF_ZQ;
  float* pv    = ws + OFF_PV;
  int*   pi    = (int*)(ws + OFF_PI);
  int*   idxw  = (int*)(ws + OFF_IDX);

  float* outp = (float*)d_out;                 // (1024 x 16384) fp32
  float* idxf = outp + (size_t)DDIM * TDIM;    // indices as float32

  // weight-norm + codebook normalize
  rownorm_kernel<<<CDIM, 256, 0, stream>>>(in_v, in_g, W_in, nullptr, DDIM, 0);
  rownorm_kernel<<<DDIM, 256, 0, stream>>>(out_v, out_g, W_out, nullptr, CDIM, 0);
  rownorm_kernel<<<KDIM, 256, 0, stream>>>(cb, nullptr, cbu, c2, CDIM, 1);

  // z_e = W_in @ z + in_b   (M=256, K=1024)
  gemm_bias<<<dim3(TDIM / 128, CDIM / 128), 256, 0, stream>>>(W_in, z, in_b, z_e, DDIM);

  // inv column norms
  colnorm_kernel<<<TDIM / 64, 256, 0, stream>>>(z_e, invn);

  // nearest-codebook argmin (k-split x8)
  dist_argmin<<<dim3(TDIM / 128, KSPLIT), 256, 0, stream>>>(z_e, invn, cbu, c2, pv, pi);
  merge_argmin<<<TDIM / 256, 256, 0, stream>>>(pv, pi, idxw, idxf);

  // STE gather into [CD][T]
  gather_zq<<<TDIM / 64, 256, 0, stream>>>(idxw, cb, z_e, zq);

  // out = W_out @ z_q + out_b   (M=1024, K=256)
  gemm_bias<<<dim3(TDIM / 128, DDIM / 128), 256, 0, stream>>>(W_out, zq, out_b, outp, CDIM);
}

// Round 5
// 611.165 us; speedup vs baseline: 11.9208x; 1.9210x over previous
//
#include <hip/hip_runtime.h>
#include <hip/hip_bf16.h>
#include <math.h>

#define TDIM 16384
#define DDIM 1024
#define CDIM 256
#define KDIM 8192
#define KSPLIT 8
#define LDA 40   // padded LDS row stride (ushorts) for 32-c chunks: 2-way banks only

typedef unsigned short u16;
typedef __attribute__((ext_vector_type(8))) short bf16x8;
typedef __attribute__((ext_vector_type(8))) unsigned short us8;
typedef __attribute__((ext_vector_type(4))) float floatx4;

// ---- workspace layout (float offsets) ----
static const size_t OFF_WIN  = 0;                                   // 256x1024 f32
static const size_t OFF_WOUT = OFF_WIN  + (size_t)CDIM * DDIM;      // 1024x256 f32
static const size_t OFF_CBU  = OFF_WOUT + (size_t)DDIM * CDIM;      // 8192x256 f32
static const size_t OFF_C2   = OFF_CBU  + (size_t)KDIM * CDIM;      // 8192 f32
static const size_t OFF_ZE   = OFF_C2   + (size_t)KDIM;             // 256x16384 f32
static const size_t OFF_INV  = OFF_ZE   + (size_t)CDIM * TDIM;      // 16384 f32
static const size_t OFF_CBH  = OFF_INV  + (size_t)TDIM;             // 8192x256 u16 (bf16 hi)
static const size_t OFF_CBL  = OFF_CBH  + (size_t)KDIM * CDIM / 2;  // 8192x256 u16 (bf16 lo)
static const size_t OFF_ETH  = OFF_CBL  + (size_t)KDIM * CDIM / 2;  // 16384x256 u16 [t][c]
static const size_t OFF_ETL  = OFF_ETH  + (size_t)TDIM * CDIM / 2;  // 16384x256 u16 [t][c]
static const size_t OFF_ZQ   = OFF_ETH;                             // 256x16384 f32 (aliases dead encT)
static const size_t OFF_PV   = OFF_ETL  + (size_t)TDIM * CDIM / 2;  // 8x16384 f32
static const size_t OFF_PI   = OFF_PV   + (size_t)KSPLIT * TDIM;    // 8x16384 i32
static const size_t OFF_IDX  = OFF_PI   + (size_t)KSPLIT * TDIM;    // 16384 i32

static __device__ __forceinline__ u16 f2bf(float x) {
  __hip_bfloat16 h = __float2bfloat16(x);
  return *(u16*)&h;
}
static __device__ __forceinline__ float bf2f(u16 u) {
  __hip_bfloat16 h; *(u16*)&h = u;
  return __bfloat162float(h);
}

// ---------------------------------------------------------------------------
// Row-wise L2 normalize: w[row] = (g?g[row]:1) * v[row] / norm(v[row])
// ---------------------------------------------------------------------------
__global__ __launch_bounds__(256) void rownorm_kernel(
    const float* __restrict__ v, const float* __restrict__ g,
    float* __restrict__ w, float* __restrict__ c2, int ncols, int clip) {
  __shared__ float red[256];
  int row = blockIdx.x;
  const float* vr = v + (size_t)row * ncols;
  float* wr = w + (size_t)row * ncols;
  float s = 0.f;
  for (int j = threadIdx.x; j < ncols; j += 256) { float x = vr[j]; s += x * x; }
  red[threadIdx.x] = s;
  __syncthreads();
  for (int off = 128; off > 0; off >>= 1) {
    if (threadIdx.x < off) red[threadIdx.x] += red[threadIdx.x + off];
    __syncthreads();
  }
  float norm = sqrtf(red[0]);
  if (clip) norm = fmaxf(norm, 1e-12f);
  float scale = (g ? g[row] : 1.0f) / norm;
  float s2 = 0.f;
  for (int j = threadIdx.x; j < ncols; j += 256) {
    float y = vr[j] * scale;
    wr[j] = y;
    s2 += y * y;
  }
  if (c2) {
    __syncthreads();
    red[threadIdx.x] = s2;
    __syncthreads();
    for (int off = 128; off > 0; off >>= 1) {
      if (threadIdx.x < off) red[threadIdx.x] += red[threadIdx.x + off];
      __syncthreads();
    }
    if (threadIdx.x == 0) c2[row] = red[0];
  }
}

// ---------------------------------------------------------------------------
// fp32 -> bf16 hi/lo split (elementwise, float4 vectorized)
// ---------------------------------------------------------------------------
__global__ __launch_bounds__(256) void split_bf16_kernel(
    const float* __restrict__ src, u16* __restrict__ hi, u16* __restrict__ lo) {
  int i = (blockIdx.x * 256 + threadIdx.x) * 4;
  float4 x = *(const float4*)&src[i];
  u16 h0 = f2bf(x.x), h1 = f2bf(x.y), h2 = f2bf(x.z), h3 = f2bf(x.w);
  u16 l0 = f2bf(x.x - bf2f(h0)), l1 = f2bf(x.y - bf2f(h1));
  u16 l2 = f2bf(x.z - bf2f(h2)), l3 = f2bf(x.w - bf2f(h3));
  ushort4 hv = {h0, h1, h2, h3}, lv = {l0, l1, l2, l3};
  *(ushort4*)&hi[i] = hv;
  *(ushort4*)&lo[i] = lv;
}

// ---------------------------------------------------------------------------
// Unified fp32 GEMM: C(M x TDIM) = A(M x K) @ B(K x TDIM) + bias[m]
// (no min-waves clause; R2 spill lesson)
// ---------------------------------------------------------------------------
__global__ __launch_bounds__(256) void gemm_bias(
    const float* __restrict__ A, const float* __restrict__ B,
    const float* __restrict__ bias, float* __restrict__ C, int K) {
  __shared__ float As[8][128];
  __shared__ float Bs[8][128];
  const int N = TDIM;
  int m0 = blockIdx.y * 128;
  int n0 = blockIdx.x * 128;
  int tid = threadIdx.x;
  int tm_lo = (tid >> 4) * 4;
  int tn_lo = (tid & 15) * 4;
  int a_r = tid >> 1, a_c = (tid & 1) * 4;
  int b_r = tid >> 5, b_c = (tid & 31) * 4;
  float acc[8][8] = {};
  float4 av = *(const float4*)&A[(size_t)(m0 + a_r) * K + a_c];
  float4 bw = *(const float4*)&B[(size_t)b_r * N + n0 + b_c];
  for (int k0 = 0; k0 < K; k0 += 8) {
    __syncthreads();
    As[a_c + 0][a_r] = av.x; As[a_c + 1][a_r] = av.y;
    As[a_c + 2][a_r] = av.z; As[a_c + 3][a_r] = av.w;
    *(float4*)&Bs[b_r][b_c] = bw;
    __syncthreads();
    if (k0 + 8 < K) {
      av = *(const float4*)&A[(size_t)(m0 + a_r) * K + k0 + 8 + a_c];
      bw = *(const float4*)&B[(size_t)(k0 + 8 + b_r) * N + n0 + b_c];
    }
#pragma unroll
    for (int kk = 0; kk < 8; kk++) {
      float a[8], b[8];
      *(float4*)&a[0] = *(const float4*)&As[kk][tm_lo];
      *(float4*)&a[4] = *(const float4*)&As[kk][tm_lo + 64];
      *(float4*)&b[0] = *(const float4*)&Bs[kk][tn_lo];
      *(float4*)&b[4] = *(const float4*)&Bs[kk][tn_lo + 64];
#pragma unroll
      for (int i = 0; i < 8; i++)
#pragma unroll
        for (int j = 0; j < 8; j++) acc[i][j] += a[i] * b[j];
    }
  }
#pragma unroll
  for (int i = 0; i < 8; i++) {
    int row = (i < 4) ? (tm_lo + i) : (tm_lo + 64 + i - 4);
    float bb = bias[m0 + row];
    float4 o0, o1;
    o0.x = acc[i][0] + bb; o0.y = acc[i][1] + bb;
    o0.z = acc[i][2] + bb; o0.w = acc[i][3] + bb;
    o1.x = acc[i][4] + bb; o1.y = acc[i][5] + bb;
    o1.z = acc[i][6] + bb; o1.w = acc[i][7] + bb;
    *(float4*)&C[(size_t)(m0 + row) * N + n0 + tn_lo] = o0;
    *(float4*)&C[(size_t)(m0 + row) * N + n0 + tn_lo + 64] = o1;
  }
}

// ---------------------------------------------------------------------------
// column norms of z_e (CD x T): inv[t] = 1/clip(||z_e[:,t]||, 1e-12)
// ---------------------------------------------------------------------------
__global__ __launch_bounds__(256) void colnorm_kernel(
    const float* __restrict__ ze, float* __restrict__ inv) {
  __shared__ float red[4][64];
  int tl = threadIdx.x & 63, part = threadIdx.x >> 6;
  int t = blockIdx.x * 64 + tl;
  float s = 0.f;
  for (int c = part * 64; c < part * 64 + 64; c++) {
    float x = ze[(size_t)c * TDIM + t];
    s += x * x;
  }
  red[part][tl] = s;
  __syncthreads();
  if (part == 0) {
    float tot = red[0][tl] + red[1][tl] + red[2][tl] + red[3][tl];
    inv[t] = 1.0f / fmaxf(sqrtf(tot), 1e-12f);
  }
}

// ---------------------------------------------------------------------------
// enc prep: encT[t][c] = bf16_split(ze[c][t] * inv[t]); LDS tile transpose.
// ---------------------------------------------------------------------------
__global__ __launch_bounds__(256) void encprep_kernel(
    const float* __restrict__ ze, const float* __restrict__ inv,
    u16* __restrict__ eth, u16* __restrict__ etl) {
  __shared__ float tile[64][65];
  int t0 = blockIdx.x * 64, c0 = blockIdx.y * 64;
  int tl = threadIdx.x & 63, grp = threadIdx.x >> 6;
  float iv = inv[t0 + tl];
#pragma unroll
  for (int r = 0; r < 16; r++) {
    int c = grp * 16 + r;
    tile[c][tl] = ze[(size_t)(c0 + c) * TDIM + t0 + tl] * iv;
  }
  __syncthreads();
#pragma unroll
  for (int r = 0; r < 16; r++) {
    int t = grp * 16 + r;
    float x = tile[tl][t];
    u16 h = f2bf(x);
    u16 l = f2bf(x - bf2f(h));
    eth[(size_t)(t0 + t) * CDIM + c0 + tl] = h;
    etl[(size_t)(t0 + t) * CDIM + c0 + tl] = l;
  }
}

// ---------------------------------------------------------------------------
// dist + argmin via split-bf16 MFMA (3 chained mfma_f32_16x16x32_bf16):
//   score(t,k) = c2[k] - 2 * enc[t]·cbu[k]
// Block: 128t x (KDIM/KSPLIT)k; k-tiles 128; c-chunks 32 staged in LDS.
// R4 BUG FIX: each staging thread covers 16 ushorts (2x us8), not 8 — the
// us8 vector is 8 ushorts (16 B); R4 left LDS columns 8-15/24-31 garbage.
// ---------------------------------------------------------------------------
__global__ __launch_bounds__(256) void dist_mfma(
    const u16* __restrict__ eth, const u16* __restrict__ etl,
    const u16* __restrict__ cbh, const u16* __restrict__ cbl,
    const float* __restrict__ c2, float* __restrict__ pv, int* __restrict__ pi) {
  __shared__ u16 Ah[128 * LDA], Al[128 * LDA];
  __shared__ u16 Bh[128 * LDA], Bl[128 * LDA];
  __shared__ float mv[2][128];
  __shared__ int   mi[2][128];
  int tid = threadIdx.x;
  int t0 = blockIdx.x * 128;
  int kbeg = blockIdx.y * (KDIM / KSPLIT);
  int lane = tid & 63, wid = tid >> 6;
  int wr = wid >> 1, wc = wid & 1;          // wave grid: wr = k-half, wc = t-half
  int q = lane >> 4, mm = lane & 15;
  int sr = tid >> 1, sh = (tid & 1) * 16;   // staging: row 0..127, 16-ushort half

  float rbv[4]; int rbi[4];
#pragma unroll
  for (int i = 0; i < 4; i++) { rbv[i] = INFINITY; rbi[i] = 0x7fffffff; }

  const floatx4 z4 = {0.f, 0.f, 0.f, 0.f};
  for (int ktile = 0; ktile < KDIM / KSPLIT; ktile += 128) {
    int k0 = kbeg + ktile;
    floatx4 acc[4][4];
#pragma unroll
    for (int i = 0; i < 4; i++)
#pragma unroll
      for (int j = 0; j < 4; j++) acc[i][j] = z4;

    for (int c0 = 0; c0 < CDIM; c0 += 32) {
      const size_t ga = (size_t)(k0 + sr) * CDIM + c0 + sh;
      const size_t gb = (size_t)(t0 + sr) * CDIM + c0 + sh;
      us8 a_h0 = *(const us8*)&cbh[ga];
      us8 a_h1 = *(const us8*)&cbh[ga + 8];
      us8 a_l0 = *(const us8*)&cbl[ga];
      us8 a_l1 = *(const us8*)&cbl[ga + 8];
      us8 b_h0 = *(const us8*)&eth[gb];
      us8 b_h1 = *(const us8*)&eth[gb + 8];
      us8 b_l0 = *(const us8*)&etl[gb];
      us8 b_l1 = *(const us8*)&etl[gb + 8];
      __syncthreads();
      *(us8*)&Ah[sr * LDA + sh]     = a_h0;
      *(us8*)&Ah[sr * LDA + sh + 8] = a_h1;
      *(us8*)&Al[sr * LDA + sh]     = a_l0;
      *(us8*)&Al[sr * LDA + sh + 8] = a_l1;
      *(us8*)&Bh[sr * LDA + sh]     = b_h0;
      *(us8*)&Bh[sr * LDA + sh + 8] = b_h1;
      *(us8*)&Bl[sr * LDA + sh]     = b_l0;
      *(us8*)&Bl[sr * LDA + sh + 8] = b_l1;
      __syncthreads();

      bf16x8 fa[4], fb[4];
#pragma unroll
      for (int i = 0; i < 4; i++)
        fa[i] = *(const bf16x8*)&Ah[(wr * 64 + i * 16 + mm) * LDA + q * 8];
#pragma unroll
      for (int j = 0; j < 4; j++)
        fb[j] = *(const bf16x8*)&Bh[(wc * 64 + j * 16 + mm) * LDA + q * 8];
      // hi x hi
#pragma unroll
      for (int i = 0; i < 4; i++)
#pragma unroll
        for (int j = 0; j < 4; j++)
          acc[i][j] = __builtin_amdgcn_mfma_f32_16x16x32_bf16(fa[i], fb[j], acc[i][j], 0, 0, 0);
      // lo x hi
#pragma unroll
      for (int i = 0; i < 4; i++) {
        bf16x8 fl = *(const bf16x8*)&Al[(wr * 64 + i * 16 + mm) * LDA + q * 8];
#pragma unroll
        for (int j = 0; j < 4; j++)
          acc[i][j] = __builtin_amdgcn_mfma_f32_16x16x32_bf16(fl, fb[j], acc[i][j], 0, 0, 0);
      }
      // hi x lo
#pragma unroll
      for (int j = 0; j < 4; j++) {
        bf16x8 fl = *(const bf16x8*)&Bl[(wc * 64 + j * 16 + mm) * LDA + q * 8];
#pragma unroll
        for (int i = 0; i < 4; i++)
          acc[i][j] = __builtin_amdgcn_mfma_f32_16x16x32_bf16(fa[i], fl, acc[i][j], 0, 0, 0);
      }
    }

    // epilogue: running per-lane argmin; k ascending in (ktile, i, r) for fixed
    // (wr, q) => strict < keeps earliest k (jnp.argmax first-max semantics)
#pragma unroll
    for (int i = 0; i < 4; i++) {
#pragma unroll
      for (int r = 0; r < 4; r++) {
        int klocal = wr * 64 + i * 16 + q * 4 + r;
        float c2v = c2[k0 + klocal];
        int kg = k0 + klocal;
#pragma unroll
        for (int j = 0; j < 4; j++) {
          float s = c2v - 2.0f * acc[i][j][r];
          if (s < rbv[j]) { rbv[j] = s; rbi[j] = kg; }
        }
      }
    }
  }

  // cross-quad merge (lanes L, L^16, L^32, L^48 share t = lane&15 per j-tile)
#pragma unroll
  for (int j = 0; j < 4; j++) {
    float v = rbv[j]; int ii = rbi[j];
    float ov = __shfl_xor(v, 16, 64); int oi = __shfl_xor(ii, 16, 64);
    if (ov < v || (ov == v && oi < ii)) { v = ov; ii = oi; }
    ov = __shfl_xor(v, 32, 64); oi = __shfl_xor(ii, 32, 64);
    if (ov < v || (ov == v && oi < ii)) { v = ov; ii = oi; }
    rbv[j] = v; rbi[j] = ii;
  }
  // cross-wave (wr) merge via LDS
  if (q == 0) {
#pragma unroll
    for (int j = 0; j < 4; j++) {
      mv[wr][wc * 64 + j * 16 + mm] = rbv[j];
      mi[wr][wc * 64 + j * 16 + mm] = rbi[j];
    }
  }
  __syncthreads();
  if (tid < 128) {
    float v0 = mv[0][tid]; int i0 = mi[0][tid];
    float v1 = mv[1][tid]; int i1 = mi[1][tid];
    if (v1 < v0 || (v1 == v0 && i1 < i0)) { v0 = v1; i0 = i1; }
    pv[(size_t)blockIdx.y * TDIM + t0 + tid] = v0;
    pi[(size_t)blockIdx.y * TDIM + t0 + tid] = i0;
  }
}

// ---------------------------------------------------------------------------
// merge k-splits; emit int idx (for gather) and float idx (output 1)
// ---------------------------------------------------------------------------
__global__ __launch_bounds__(256) void merge_argmin(
    const float* __restrict__ pv, const int* __restrict__ pi,
    int* __restrict__ idx, float* __restrict__ idxf) {
  int t = blockIdx.x * 256 + threadIdx.x;
  float bv = INFINITY; int bi = 0x7fffffff;
  for (int s = 0; s < KSPLIT; s++) {
    float v = pv[(size_t)s * TDIM + t];
    int ii = pi[(size_t)s * TDIM + t];
    if (v < bv || (v == bv && ii < bi)) { bv = v; bi = ii; }
  }
  idx[t] = bi;
  idxf[t] = (float)bi;
}

// ---------------------------------------------------------------------------
// STE gather into [CD][T]: zq[c][t] = ze[c][t] + (cb[idx[t]][c] - ze[c][t])
// ---------------------------------------------------------------------------
__global__ __launch_bounds__(256) void gather_zq(
    const int* __restrict__ idx, const float* __restrict__ cb,
    const float* __restrict__ ze, float* __restrict__ zq) {
  int tl = threadIdx.x & 63, cgrp = threadIdx.x >> 6;
  int t = blockIdx.x * 64 + tl;
  int k = idx[t];
  const float* cbr = cb + (size_t)k * CDIM;
  for (int c = cgrp * 64; c < cgrp * 64 + 64; c++) {
    float cbv = cbr[c];
    float zev = ze[(size_t)c * TDIM + t];
    zq[(size_t)c * TDIM + t] = zev + (cbv - zev);
  }
}

extern "C" void kernel_launch(void* const* d_in, const int* in_sizes, int n_in,
                              void* d_out, int out_size, void* d_ws, size_t ws_size,
                              hipStream_t stream) {
  const float* z     = (const float*)d_in[0];
  const float* in_v  = (const float*)d_in[1];
  const float* in_g  = (const float*)d_in[2];
  const float* in_b  = (const float*)d_in[3];
  const float* out_v = (const float*)d_in[4];
  const float* out_g = (const float*)d_in[5];
  const float* out_b = (const float*)d_in[6];
  const float* cb    = (const float*)d_in[7];

  float* ws    = (float*)d_ws;
  float* W_in  = ws + OFF_WIN;
  float* W_out = ws + OFF_WOUT;
  float* cbu   = ws + OFF_CBU;
  float* c2    = ws + OFF_C2;
  float* z_e   = ws + OFF_ZE;
  float* invn  = ws + OFF_INV;
  u16*   cbh   = (u16*)(ws + OFF_CBH);
  u16*   cbl   = (u16*)(ws + OFF_CBL);
  u16*   eth   = (u16*)(ws + OFF_ETH);
  u16*   etl   = (u16*)(ws + OFF_ETL);
  float* zq    = ws + OFF_ZQ;              // aliases eth/etl (dead after dist)
  float* pv    = ws + OFF_PV;
  int*   pi    = (int*)(ws + OFF_PI);
  int*   idxw  = (int*)(ws + OFF_IDX);

  float* outp = (float*)d_out;                 // (1024 x 16384) fp32
  float* idxf = outp + (size_t)DDIM * TDIM;    // indices as float32

  // weight-norm + codebook normalize (+ exact c2 of rounded cbu)
  rownorm_kernel<<<CDIM, 256, 0, stream>>>(in_v, in_g, W_in, nullptr, DDIM, 0);
  rownorm_kernel<<<DDIM, 256, 0, stream>>>(out_v, out_g, W_out, nullptr, CDIM, 0);
  rownorm_kernel<<<KDIM, 256, 0, stream>>>(cb, nullptr, cbu, c2, CDIM, 1);

  // bf16 hi/lo split of normalized codebook
  split_bf16_kernel<<<(KDIM * CDIM / 4) / 256, 256, 0, stream>>>(cbu, cbh, cbl);

  // z_e = W_in @ z + in_b   (M=256, K=1024)
  gemm_bias<<<dim3(TDIM / 128, CDIM / 128), 256, 0, stream>>>(W_in, z, in_b, z_e, DDIM);

  // inv column norms, then enc transpose+split to [t][c] bf16 hi/lo
  colnorm_kernel<<<TDIM / 64, 256, 0, stream>>>(z_e, invn);
  encprep_kernel<<<dim3(TDIM / 64, CDIM / 64), 256, 0, stream>>>(z_e, invn, eth, etl);

  // nearest-codebook argmin via split-bf16 MFMA (k-split x8)
  dist_mfma<<<dim3(TDIM / 128, KSPLIT), 256, 0, stream>>>(eth, etl, cbh, cbl, c2, pv, pi);
  merge_argmin<<<TDIM / 256, 256, 0, stream>>>(pv, pi, idxw, idxf);

  // STE gather into [CD][T] (zq aliases encT region — dist already done)
  gather_zq<<<TDIM / 64, 256, 0, stream>>>(idxw, cb, z_e, zq);

  // out = W_out @ z_q + out_b   (M=1024, K=256)
  gemm_bias<<<dim3(TDIM / 128, DDIM / 128), 256, 0, stream>>>(W_out, zq, out_b, outp, CDIM);
}

// Round 6
// 532.255 us; speedup vs baseline: 13.6882x; 1.1483x over previous
//
#include <hip/hip_runtime.h>
#include <hip/hip_bf16.h>
#include <math.h>

#define TDIM 16384
#define DDIM 1024
#define CDIM 256
#define KDIM 8192
#define KSPLIT 8

typedef unsigned short u16;
typedef __attribute__((ext_vector_type(8))) short bf16x8;
typedef __attribute__((ext_vector_type(8))) unsigned short us8;
typedef __attribute__((ext_vector_type(4))) float floatx4;

// ---- workspace layout (float offsets) ----
static const size_t OFF_WIN   = 0;                                    // 256x1024 f32
static const size_t OFF_CBU   = OFF_WIN   + (size_t)CDIM * DDIM;      // 8192x256 f32
static const size_t OFF_C2    = OFF_CBU   + (size_t)KDIM * CDIM;      // 8192 f32
static const size_t OFF_ZE    = OFF_C2    + (size_t)KDIM;             // 256x16384 f32
static const size_t OFF_INV   = OFF_ZE    + (size_t)CDIM * TDIM;      // 16384 f32
static const size_t OFF_CBH   = OFF_INV   + (size_t)TDIM;             // 8192x256 u16
static const size_t OFF_CBL   = OFF_CBH   + (size_t)KDIM * CDIM / 2;  // 8192x256 u16
static const size_t OFF_ETH   = OFF_CBL   + (size_t)KDIM * CDIM / 2;  // 16384x256 u16 [t][c]
static const size_t OFF_ETL   = OFF_ETH   + (size_t)TDIM * CDIM / 2;  // 16384x256 u16 [t][c]
static const size_t OFF_PV    = OFF_ETL   + (size_t)TDIM * CDIM / 2;  // 8x16384 f32
static const size_t OFF_PI    = OFF_PV    + (size_t)KSPLIT * TDIM;    // 8x16384 i32
static const size_t OFF_IDX   = OFF_PI    + (size_t)KSPLIT * TDIM;    // 16384 i32
static const size_t OFF_WOUTH = OFF_IDX   + (size_t)TDIM;             // 1024x256 u16
static const size_t OFF_WOUTL = OFF_WOUTH + (size_t)DDIM * CDIM / 2;  // 1024x256 u16
// zqT hi/lo alias ETH/ETL (dead after dist_mfma)

static __device__ __forceinline__ u16 f2bf(float x) {
  __hip_bfloat16 h = __float2bfloat16(x);
  return *(u16*)&h;
}
static __device__ __forceinline__ float bf2f(u16 u) {
  __hip_bfloat16 h; *(u16*)&h = u;
  return __bfloat162float(h);
}

// ---------------------------------------------------------------------------
// Row-wise L2 normalize (f32 out): w = (g?g:1) * v / norm; optional clip+c2.
// ---------------------------------------------------------------------------
__global__ __launch_bounds__(256) void rownorm_kernel(
    const float* __restrict__ v, const float* __restrict__ g,
    float* __restrict__ w, float* __restrict__ c2, int ncols, int clip) {
  __shared__ float red[256];
  int row = blockIdx.x;
  const float* vr = v + (size_t)row * ncols;
  float* wr = w + (size_t)row * ncols;
  float s = 0.f;
  for (int j = threadIdx.x; j < ncols; j += 256) { float x = vr[j]; s += x * x; }
  red[threadIdx.x] = s;
  __syncthreads();
  for (int off = 128; off > 0; off >>= 1) {
    if (threadIdx.x < off) red[threadIdx.x] += red[threadIdx.x + off];
    __syncthreads();
  }
  float norm = sqrtf(red[0]);
  if (clip) norm = fmaxf(norm, 1e-12f);
  float scale = (g ? g[row] : 1.0f) / norm;
  float s2 = 0.f;
  for (int j = threadIdx.x; j < ncols; j += 256) {
    float y = vr[j] * scale;
    wr[j] = y;
    s2 += y * y;
  }
  if (c2) {
    __syncthreads();
    red[threadIdx.x] = s2;
    __syncthreads();
    for (int off = 128; off > 0; off >>= 1) {
      if (threadIdx.x < off) red[threadIdx.x] += red[threadIdx.x + off];
      __syncthreads();
    }
    if (threadIdx.x == 0) c2[row] = red[0];
  }
}

// ---------------------------------------------------------------------------
// Row-wise L2 normalize -> bf16 hi/lo split (for W_out; ncols == 256)
// ---------------------------------------------------------------------------
__global__ __launch_bounds__(256) void rownorm_split_kernel(
    const float* __restrict__ v, const float* __restrict__ g,
    u16* __restrict__ hi, u16* __restrict__ lo) {
  __shared__ float red[256];
  int row = blockIdx.x;
  const float* vr = v + (size_t)row * CDIM;
  float x = vr[threadIdx.x];
  red[threadIdx.x] = x * x;
  __syncthreads();
  for (int off = 128; off > 0; off >>= 1) {
    if (threadIdx.x < off) red[threadIdx.x] += red[threadIdx.x + off];
    __syncthreads();
  }
  float scale = g[row] / sqrtf(red[0]);
  float y = x * scale;
  u16 hh = f2bf(y);
  u16 ll = f2bf(y - bf2f(hh));
  hi[(size_t)row * CDIM + threadIdx.x] = hh;
  lo[(size_t)row * CDIM + threadIdx.x] = ll;
}

// ---------------------------------------------------------------------------
// fp32 -> bf16 hi/lo split (elementwise)
// ---------------------------------------------------------------------------
__global__ __launch_bounds__(256) void split_bf16_kernel(
    const float* __restrict__ src, u16* __restrict__ hi, u16* __restrict__ lo) {
  int i = (blockIdx.x * 256 + threadIdx.x) * 4;
  float4 x = *(const float4*)&src[i];
  u16 h0 = f2bf(x.x), h1 = f2bf(x.y), h2 = f2bf(x.z), h3 = f2bf(x.w);
  u16 l0 = f2bf(x.x - bf2f(h0)), l1 = f2bf(x.y - bf2f(h1));
  u16 l2 = f2bf(x.z - bf2f(h2)), l3 = f2bf(x.w - bf2f(h3));
  ushort4 hv = {h0, h1, h2, h3}, lv = {l0, l1, l2, l3};
  *(ushort4*)&hi[i] = hv;
  *(ushort4*)&lo[i] = lv;
}

// ---------------------------------------------------------------------------
// fp32 GEMM (in_proj): C(M x TDIM) = A(M x K) @ B(K x TDIM) + bias[m]
// (no min-waves clause; R2 spill lesson)
// ---------------------------------------------------------------------------
__global__ __launch_bounds__(256) void gemm_bias(
    const float* __restrict__ A, const float* __restrict__ B,
    const float* __restrict__ bias, float* __restrict__ C, int K) {
  __shared__ float As[8][128];
  __shared__ float Bs[8][128];
  const int N = TDIM;
  int m0 = blockIdx.y * 128;
  int n0 = blockIdx.x * 128;
  int tid = threadIdx.x;
  int tm_lo = (tid >> 4) * 4;
  int tn_lo = (tid & 15) * 4;
  int a_r = tid >> 1, a_c = (tid & 1) * 4;
  int b_r = tid >> 5, b_c = (tid & 31) * 4;
  float acc[8][8] = {};
  float4 av = *(const float4*)&A[(size_t)(m0 + a_r) * K + a_c];
  float4 bw = *(const float4*)&B[(size_t)b_r * N + n0 + b_c];
  for (int k0 = 0; k0 < K; k0 += 8) {
    __syncthreads();
    As[a_c + 0][a_r] = av.x; As[a_c + 1][a_r] = av.y;
    As[a_c + 2][a_r] = av.z; As[a_c + 3][a_r] = av.w;
    *(float4*)&Bs[b_r][b_c] = bw;
    __syncthreads();
    if (k0 + 8 < K) {
      av = *(const float4*)&A[(size_t)(m0 + a_r) * K + k0 + 8 + a_c];
      bw = *(const float4*)&B[(size_t)(k0 + 8 + b_r) * N + n0 + b_c];
    }
#pragma unroll
    for (int kk = 0; kk < 8; kk++) {
      float a[8], b[8];
      *(float4*)&a[0] = *(const float4*)&As[kk][tm_lo];
      *(float4*)&a[4] = *(const float4*)&As[kk][tm_lo + 64];
      *(float4*)&b[0] = *(const float4*)&Bs[kk][tn_lo];
      *(float4*)&b[4] = *(const float4*)&Bs[kk][tn_lo + 64];
#pragma unroll
      for (int i = 0; i < 8; i++)
#pragma unroll
        for (int j = 0; j < 8; j++) acc[i][j] += a[i] * b[j];
    }
  }
#pragma unroll
  for (int i = 0; i < 8; i++) {
    int row = (i < 4) ? (tm_lo + i) : (tm_lo + 64 + i - 4);
    float bb = bias[m0 + row];
    float4 o0, o1;
    o0.x = acc[i][0] + bb; o0.y = acc[i][1] + bb;
    o0.z = acc[i][2] + bb; o0.w = acc[i][3] + bb;
    o1.x = acc[i][4] + bb; o1.y = acc[i][5] + bb;
    o1.z = acc[i][6] + bb; o1.w = acc[i][7] + bb;
    *(float4*)&C[(size_t)(m0 + row) * N + n0 + tn_lo] = o0;
    *(float4*)&C[(size_t)(m0 + row) * N + n0 + tn_lo + 64] = o1;
  }
}

// ---------------------------------------------------------------------------
// column norms of z_e (CD x T): inv[t] = 1/clip(||z_e[:,t]||, 1e-12)
// ---------------------------------------------------------------------------
__global__ __launch_bounds__(256) void colnorm_kernel(
    const float* __restrict__ ze, float* __restrict__ inv) {
  __shared__ float red[4][64];
  int tl = threadIdx.x & 63, part = threadIdx.x >> 6;
  int t = blockIdx.x * 64 + tl;
  float s = 0.f;
  for (int c = part * 64; c < part * 64 + 64; c++) {
    float x = ze[(size_t)c * TDIM + t];
    s += x * x;
  }
  red[part][tl] = s;
  __syncthreads();
  if (part == 0) {
    float tot = red[0][tl] + red[1][tl] + red[2][tl] + red[3][tl];
    inv[t] = 1.0f / fmaxf(sqrtf(tot), 1e-12f);
  }
}

// ---------------------------------------------------------------------------
// enc prep: encT[t][c] = bf16_split(ze[c][t] * inv[t]); LDS tile transpose.
// ---------------------------------------------------------------------------
__global__ __launch_bounds__(256) void encprep_kernel(
    const float* __restrict__ ze, const float* __restrict__ inv,
    u16* __restrict__ eth, u16* __restrict__ etl) {
  __shared__ float tile[64][65];
  int t0 = blockIdx.x * 64, c0 = blockIdx.y * 64;
  int tl = threadIdx.x & 63, grp = threadIdx.x >> 6;
  float iv = inv[t0 + tl];
#pragma unroll
  for (int r = 0; r < 16; r++) {
    int c = grp * 16 + r;
    tile[c][tl] = ze[(size_t)(c0 + c) * TDIM + t0 + tl] * iv;
  }
  __syncthreads();
#pragma unroll
  for (int r = 0; r < 16; r++) {
    int t = grp * 16 + r;
    float x = tile[tl][t];
    u16 h = f2bf(x);
    u16 l = f2bf(x - bf2f(h));
    eth[(size_t)(t0 + t) * CDIM + c0 + tl] = h;
    etl[(size_t)(t0 + t) * CDIM + c0 + tl] = l;
  }
}

// ---------------------------------------------------------------------------
// XOR-swizzled 128x32-u16 LDS tile (no padding):
//   P(r, b, w) = r*32 + ((b ^ s(r))*8) + w,  s(r) = (r ^ (r>>2)) & 3
// Staging rows r = (tid>>1) ^ ((tid&1)<<2): every 8-lane window of both the
// us8 writes and the b128 fragment reads hits 8 distinct 4-word bank groups
// (enumerated by hand) -> minimum-cycle LDS, ~20% cycle win vs R5's pad-40.
// ---------------------------------------------------------------------------

// dist + argmin via split-bf16 MFMA (3 chained mfma_f32_16x16x32_bf16)
__global__ __launch_bounds__(256) void dist_mfma(
    const u16* __restrict__ eth, const u16* __restrict__ etl,
    const u16* __restrict__ cbh, const u16* __restrict__ cbl,
    const float* __restrict__ c2, float* __restrict__ pv, int* __restrict__ pi) {
  __shared__ u16 Ah[128 * 32], Al[128 * 32];
  __shared__ u16 Bh[128 * 32], Bl[128 * 32];
  __shared__ float mv[2][128];
  __shared__ int   mi[2][128];
  int tid = threadIdx.x;
  int t0 = blockIdx.x * 128;
  int kbeg = blockIdx.y * (KDIM / KSPLIT);
  int lane = tid & 63, wid = tid >> 6;
  int wr = wid >> 1, wc = wid & 1;          // wave grid: wr = k-half, wc = t-half
  int q = lane >> 4, mm = lane & 15;
  // staging assignment (swizzled)
  int h = tid & 1;
  int sr = ((tid >> 1) ^ (h << 2)) & 127;
  int ssw = (sr ^ (sr >> 2)) & 3;
  int o0 = sr * 32 + ((((h << 1))     ^ ssw) << 3);
  int o1 = sr * 32 + ((((h << 1) | 1) ^ ssw) << 3);
  int gcol = h * 16;
  // fragment read offsets
  int sm = (mm ^ (mm >> 2)) & 3;
  int cq = (q ^ sm) << 3;

  float rbv[4]; int rbi[4];
#pragma unroll
  for (int i = 0; i < 4; i++) { rbv[i] = INFINITY; rbi[i] = 0x7fffffff; }

  const floatx4 z4 = {0.f, 0.f, 0.f, 0.f};
  for (int ktile = 0; ktile < KDIM / KSPLIT; ktile += 128) {
    int k0 = kbeg + ktile;
    floatx4 acc[4][4];
#pragma unroll
    for (int i = 0; i < 4; i++)
#pragma unroll
      for (int j = 0; j < 4; j++) acc[i][j] = z4;

    for (int c0 = 0; c0 < CDIM; c0 += 32) {
      const size_t ga = (size_t)(k0 + sr) * CDIM + c0 + gcol;
      const size_t gb = (size_t)(t0 + sr) * CDIM + c0 + gcol;
      us8 a_h0 = *(const us8*)&cbh[ga];
      us8 a_h1 = *(const us8*)&cbh[ga + 8];
      us8 a_l0 = *(const us8*)&cbl[ga];
      us8 a_l1 = *(const us8*)&cbl[ga + 8];
      us8 b_h0 = *(const us8*)&eth[gb];
      us8 b_h1 = *(const us8*)&eth[gb + 8];
      us8 b_l0 = *(const us8*)&etl[gb];
      us8 b_l1 = *(const us8*)&etl[gb + 8];
      __syncthreads();
      *(us8*)&Ah[o0] = a_h0; *(us8*)&Ah[o1] = a_h1;
      *(us8*)&Al[o0] = a_l0; *(us8*)&Al[o1] = a_l1;
      *(us8*)&Bh[o0] = b_h0; *(us8*)&Bh[o1] = b_h1;
      *(us8*)&Bl[o0] = b_l0; *(us8*)&Bl[o1] = b_l1;
      __syncthreads();

      bf16x8 fa[4], fb[4];
#pragma unroll
      for (int i = 0; i < 4; i++)
        fa[i] = *(const bf16x8*)&Ah[(wr * 64 + i * 16 + mm) * 32 + cq];
#pragma unroll
      for (int j = 0; j < 4; j++)
        fb[j] = *(const bf16x8*)&Bh[(wc * 64 + j * 16 + mm) * 32 + cq];
      // hi x hi
#pragma unroll
      for (int i = 0; i < 4; i++)
#pragma unroll
        for (int j = 0; j < 4; j++)
          acc[i][j] = __builtin_amdgcn_mfma_f32_16x16x32_bf16(fa[i], fb[j], acc[i][j], 0, 0, 0);
      // lo x hi
#pragma unroll
      for (int i = 0; i < 4; i++) {
        bf16x8 fl = *(const bf16x8*)&Al[(wr * 64 + i * 16 + mm) * 32 + cq];
#pragma unroll
        for (int j = 0; j < 4; j++)
          acc[i][j] = __builtin_amdgcn_mfma_f32_16x16x32_bf16(fl, fb[j], acc[i][j], 0, 0, 0);
      }
      // hi x lo
#pragma unroll
      for (int j = 0; j < 4; j++) {
        bf16x8 fl = *(const bf16x8*)&Bl[(wc * 64 + j * 16 + mm) * 32 + cq];
#pragma unroll
        for (int i = 0; i < 4; i++)
          acc[i][j] = __builtin_amdgcn_mfma_f32_16x16x32_bf16(fa[i], fl, acc[i][j], 0, 0, 0);
      }
    }

    // running per-lane argmin; k ascending in (ktile, i, r) => earliest k wins
#pragma unroll
    for (int i = 0; i < 4; i++) {
#pragma unroll
      for (int r = 0; r < 4; r++) {
        int klocal = wr * 64 + i * 16 + q * 4 + r;
        float c2v = c2[k0 + klocal];
        int kg = k0 + klocal;
#pragma unroll
        for (int j = 0; j < 4; j++) {
          float s = c2v - 2.0f * acc[i][j][r];
          if (s < rbv[j]) { rbv[j] = s; rbi[j] = kg; }
        }
      }
    }
  }

  // cross-quad merge (lanes L, L^16, L^32, L^48 share t = lane&15 per j-tile)
#pragma unroll
  for (int j = 0; j < 4; j++) {
    float v = rbv[j]; int ii = rbi[j];
    float ov = __shfl_xor(v, 16, 64); int oi = __shfl_xor(ii, 16, 64);
    if (ov < v || (ov == v && oi < ii)) { v = ov; ii = oi; }
    ov = __shfl_xor(v, 32, 64); oi = __shfl_xor(ii, 32, 64);
    if (ov < v || (ov == v && oi < ii)) { v = ov; ii = oi; }
    rbv[j] = v; rbi[j] = ii;
  }
  if (q == 0) {
#pragma unroll
    for (int j = 0; j < 4; j++) {
      mv[wr][wc * 64 + j * 16 + mm] = rbv[j];
      mi[wr][wc * 64 + j * 16 + mm] = rbi[j];
    }
  }
  __syncthreads();
  if (tid < 128) {
    float v0 = mv[0][tid]; int i0 = mi[0][tid];
    float v1 = mv[1][tid]; int i1 = mi[1][tid];
    if (v1 < v0 || (v1 == v0 && i1 < i0)) { v0 = v1; i0 = i1; }
    pv[(size_t)blockIdx.y * TDIM + t0 + tid] = v0;
    pi[(size_t)blockIdx.y * TDIM + t0 + tid] = i0;
  }
}

// ---------------------------------------------------------------------------
// merge k-splits; emit int idx (for gather) and float idx (output 1)
// ---------------------------------------------------------------------------
__global__ __launch_bounds__(256) void merge_argmin(
    const float* __restrict__ pv, const int* __restrict__ pi,
    int* __restrict__ idx, float* __restrict__ idxf) {
  int t = blockIdx.x * 256 + threadIdx.x;
  float bv = INFINITY; int bi = 0x7fffffff;
  for (int s = 0; s < KSPLIT; s++) {
    float v = pv[(size_t)s * TDIM + t];
    int ii = pi[(size_t)s * TDIM + t];
    if (v < bv || (v == bv && ii < bi)) { bv = v; bi = ii; }
  }
  idx[t] = bi;
  idxf[t] = (float)bi;
}

// ---------------------------------------------------------------------------
// STE gather -> zqT [t][c] bf16 hi/lo (LDS transpose):
//   zq = ze + (cb[idx[t]][c] - ze)  computed fp32, then split.
// ---------------------------------------------------------------------------
__global__ __launch_bounds__(256) void gather_zqT(
    const int* __restrict__ idx, const float* __restrict__ cb,
    const float* __restrict__ ze, u16* __restrict__ zqh, u16* __restrict__ zql) {
  __shared__ float tile[64][65];
  int t0 = blockIdx.x * 64, c0 = blockIdx.y * 64;
  int tl = threadIdx.x & 63, grp = threadIdx.x >> 6;
#pragma unroll
  for (int r = 0; r < 16; r++) {
    int c = grp * 16 + r;
    tile[c][tl] = ze[(size_t)(c0 + c) * TDIM + t0 + tl];
  }
  __syncthreads();
#pragma unroll
  for (int r = 0; r < 16; r++) {
    int t = grp * 16 + r;
    int tg = t0 + t;
    int k = idx[tg];
    float zev = tile[tl][t];
    float cbv = cb[(size_t)k * CDIM + c0 + tl];
    float zqv = zev + (cbv - zev);
    u16 hh = f2bf(zqv);
    u16 ll = f2bf(zqv - bf2f(hh));
    zqh[(size_t)tg * CDIM + c0 + tl] = hh;
    zql[(size_t)tg * CDIM + c0 + tl] = ll;
  }
}

// ---------------------------------------------------------------------------
// out_proj via split-bf16 MFMA: C[m][t] = Wout[m]·zq[t] + bias[m]
// A = wouth/woutl [1024][256], B = zqh/zql [16384][256]; same swizzled tiles.
// ---------------------------------------------------------------------------
__global__ __launch_bounds__(256) void gemm_mfma_out(
    const u16* __restrict__ ah_g, const u16* __restrict__ al_g,
    const u16* __restrict__ bh_g, const u16* __restrict__ bl_g,
    const float* __restrict__ bias, float* __restrict__ C) {
  __shared__ u16 Ah[128 * 32], Al[128 * 32];
  __shared__ u16 Bh[128 * 32], Bl[128 * 32];
  int tid = threadIdx.x;
  int n0 = blockIdx.x * 128;     // t
  int m0 = blockIdx.y * 128;     // D rows
  int lane = tid & 63, wid = tid >> 6;
  int wr = wid >> 1, wc = wid & 1;
  int q = lane >> 4, mm = lane & 15;
  int h = tid & 1;
  int sr = ((tid >> 1) ^ (h << 2)) & 127;
  int ssw = (sr ^ (sr >> 2)) & 3;
  int o0 = sr * 32 + ((((h << 1))     ^ ssw) << 3);
  int o1 = sr * 32 + ((((h << 1) | 1) ^ ssw) << 3);
  int gcol = h * 16;
  int sm = (mm ^ (mm >> 2)) & 3;
  int cq = (q ^ sm) << 3;

  const floatx4 z4 = {0.f, 0.f, 0.f, 0.f};
  floatx4 acc[4][4];
#pragma unroll
  for (int i = 0; i < 4; i++)
#pragma unroll
    for (int j = 0; j < 4; j++) acc[i][j] = z4;

  for (int c0 = 0; c0 < CDIM; c0 += 32) {
    const size_t ga = (size_t)(m0 + sr) * CDIM + c0 + gcol;
    const size_t gb = (size_t)(n0 + sr) * CDIM + c0 + gcol;
    us8 a_h0 = *(const us8*)&ah_g[ga];
    us8 a_h1 = *(const us8*)&ah_g[ga + 8];
    us8 a_l0 = *(const us8*)&al_g[ga];
    us8 a_l1 = *(const us8*)&al_g[ga + 8];
    us8 b_h0 = *(const us8*)&bh_g[gb];
    us8 b_h1 = *(const us8*)&bh_g[gb + 8];
    us8 b_l0 = *(const us8*)&bl_g[gb];
    us8 b_l1 = *(const us8*)&bl_g[gb + 8];
    __syncthreads();
    *(us8*)&Ah[o0] = a_h0; *(us8*)&Ah[o1] = a_h1;
    *(us8*)&Al[o0] = a_l0; *(us8*)&Al[o1] = a_l1;
    *(us8*)&Bh[o0] = b_h0; *(us8*)&Bh[o1] = b_h1;
    *(us8*)&Bl[o0] = b_l0; *(us8*)&Bl[o1] = b_l1;
    __syncthreads();

    bf16x8 fa[4], fb[4];
#pragma unroll
    for (int i = 0; i < 4; i++)
      fa[i] = *(const bf16x8*)&Ah[(wr * 64 + i * 16 + mm) * 32 + cq];
#pragma unroll
    for (int j = 0; j < 4; j++)
      fb[j] = *(const bf16x8*)&Bh[(wc * 64 + j * 16 + mm) * 32 + cq];
#pragma unroll
    for (int i = 0; i < 4; i++)
#pragma unroll
      for (int j = 0; j < 4; j++)
        acc[i][j] = __builtin_amdgcn_mfma_f32_16x16x32_bf16(fa[i], fb[j], acc[i][j], 0, 0, 0);
#pragma unroll
    for (int i = 0; i < 4; i++) {
      bf16x8 fl = *(const bf16x8*)&Al[(wr * 64 + i * 16 + mm) * 32 + cq];
#pragma unroll
      for (int j = 0; j < 4; j++)
        acc[i][j] = __builtin_amdgcn_mfma_f32_16x16x32_bf16(fl, fb[j], acc[i][j], 0, 0, 0);
    }
#pragma unroll
    for (int j = 0; j < 4; j++) {
      bf16x8 fl = *(const bf16x8*)&Bl[(wc * 64 + j * 16 + mm) * 32 + cq];
#pragma unroll
      for (int i = 0; i < 4; i++)
        acc[i][j] = __builtin_amdgcn_mfma_f32_16x16x32_bf16(fa[i], fl, acc[i][j], 0, 0, 0);
    }
  }

  // epilogue: C[m][n] row = wr*64+i*16+q*4+r, col = wc*64+j*16+mm
#pragma unroll
  for (int i = 0; i < 4; i++) {
#pragma unroll
    for (int r = 0; r < 4; r++) {
      int m_loc = wr * 64 + i * 16 + q * 4 + r;
      float bb = bias[m0 + m_loc];
      float* crow = &C[(size_t)(m0 + m_loc) * TDIM + n0 + wc * 64 + mm];
#pragma unroll
      for (int j = 0; j < 4; j++) crow[j * 16] = acc[i][j][r] + bb;
    }
  }
}

extern "C" void kernel_launch(void* const* d_in, const int* in_sizes, int n_in,
                              void* d_out, int out_size, void* d_ws, size_t ws_size,
                              hipStream_t stream) {
  const float* z     = (const float*)d_in[0];
  const float* in_v  = (const float*)d_in[1];
  const float* in_g  = (const float*)d_in[2];
  const float* in_b  = (const float*)d_in[3];
  const float* out_v = (const float*)d_in[4];
  const float* out_g = (const float*)d_in[5];
  const float* out_b = (const float*)d_in[6];
  const float* cb    = (const float*)d_in[7];

  float* ws    = (float*)d_ws;
  float* W_in  = ws + OFF_WIN;
  float* cbu   = ws + OFF_CBU;
  float* c2    = ws + OFF_C2;
  float* z_e   = ws + OFF_ZE;
  float* invn  = ws + OFF_INV;
  u16*   cbh   = (u16*)(ws + OFF_CBH);
  u16*   cbl   = (u16*)(ws + OFF_CBL);
  u16*   eth   = (u16*)(ws + OFF_ETH);
  u16*   etl   = (u16*)(ws + OFF_ETL);
  u16*   zqh   = (u16*)(ws + OFF_ETH);   // alias: eth dead after dist_mfma
  u16*   zql   = (u16*)(ws + OFF_ETL);   // alias: etl dead after dist_mfma
  float* pv    = ws + OFF_PV;
  int*   pi    = (int*)(ws + OFF_PI);
  int*   idxw  = (int*)(ws + OFF_IDX);
  u16*   wouth = (u16*)(ws + OFF_WOUTH);
  u16*   woutl = (u16*)(ws + OFF_WOUTL);

  float* outp = (float*)d_out;                 // (1024 x 16384) fp32
  float* idxf = outp + (size_t)DDIM * TDIM;    // indices as float32

  // weight-norm: W_in f32; W_out directly split; codebook f32 + c2
  rownorm_kernel<<<CDIM, 256, 0, stream>>>(in_v, in_g, W_in, nullptr, DDIM, 0);
  rownorm_split_kernel<<<DDIM, 256, 0, stream>>>(out_v, out_g, wouth, woutl);
  rownorm_kernel<<<KDIM, 256, 0, stream>>>(cb, nullptr, cbu, c2, CDIM, 1);
  split_bf16_kernel<<<(KDIM * CDIM / 4) / 256, 256, 0, stream>>>(cbu, cbh, cbl);

  // z_e = W_in @ z + in_b   (fp32; M=256, K=1024)
  gemm_bias<<<dim3(TDIM / 128, CDIM / 128), 256, 0, stream>>>(W_in, z, in_b, z_e, DDIM);

  // inv column norms + enc transpose/split
  colnorm_kernel<<<TDIM / 64, 256, 0, stream>>>(z_e, invn);
  encprep_kernel<<<dim3(TDIM / 64, CDIM / 64), 256, 0, stream>>>(z_e, invn, eth, etl);

  // nearest-codebook argmin (k-split x8)
  dist_mfma<<<dim3(TDIM / 128, KSPLIT), 256, 0, stream>>>(eth, etl, cbh, cbl, c2, pv, pi);
  merge_argmin<<<TDIM / 256, 256, 0, stream>>>(pv, pi, idxw, idxf);

  // STE gather -> zqT split (aliases encT region)
  gather_zqT<<<dim3(TDIM / 64, CDIM / 64), 256, 0, stream>>>(idxw, cb, z_e, zqh, zql);

  // out = W_out @ z_q + out_b  (split-bf16 MFMA; M=1024, K=256)
  gemm_mfma_out<<<dim3(TDIM / 128, DDIM / 128), 256, 0, stream>>>(
      wouth, woutl, zqh, zql, out_b, outp);
}

// Round 7
// 470.037 us; speedup vs baseline: 15.5000x; 1.1324x over previous
//
#include <hip/hip_runtime.h>
#include <hip/hip_bf16.h>
#include <math.h>

#define TDIM 16384
#define DDIM 1024
#define CDIM 256
#define KDIM 8192
#define KSPLIT 8

typedef unsigned short u16;
typedef __attribute__((ext_vector_type(8))) short bf16x8;
typedef __attribute__((ext_vector_type(8))) unsigned short us8;
typedef __attribute__((ext_vector_type(4))) float floatx4;

// ---- workspace layout (float offsets) ----
static const size_t OFF_WINH  = 0;                                     // 256x1024 u16
static const size_t OFF_WINL  = OFF_WINH  + (size_t)CDIM * DDIM / 2;
static const size_t OFF_WOUTH = OFF_WINL  + (size_t)CDIM * DDIM / 2;   // 1024x256 u16
static const size_t OFF_WOUTL = OFF_WOUTH + (size_t)DDIM * CDIM / 2;
static const size_t OFF_CBH   = OFF_WOUTL + (size_t)DDIM * CDIM / 2;   // 8192x256 u16
static const size_t OFF_CBL   = OFF_CBH   + (size_t)KDIM * CDIM / 2;
static const size_t OFF_C2    = OFF_CBL   + (size_t)KDIM * CDIM / 2;   // 8192 f32
static const size_t OFF_ZTH   = OFF_C2    + (size_t)KDIM;              // 16384x1024 u16 [t][d]
static const size_t OFF_ZTL   = OFF_ZTH   + (size_t)TDIM * DDIM / 2;
static const size_t OFF_ZE    = OFF_ZTL   + (size_t)TDIM * DDIM / 2;   // 256x16384 f32
static const size_t OFF_PV    = OFF_ZE    + (size_t)CDIM * TDIM;       // 8x16384 f32
static const size_t OFF_PI    = OFF_PV    + (size_t)KSPLIT * TDIM;     // 8x16384 i32
static const size_t OFF_IDX   = OFF_PI    + (size_t)KSPLIT * TDIM;     // 16384 i32
// eth/etl [t][c] alias ZTH (zth/ztl dead after in_proj gemm);
// zqh/zql alias the same region again (eth/etl dead after dist_mfma).
static const size_t OFF_ETH   = OFF_ZTH;
static const size_t OFF_ETL   = OFF_ZTH + (size_t)TDIM * CDIM / 2;

static __device__ __forceinline__ u16 f2bf(float x) {
  __hip_bfloat16 h = __float2bfloat16(x);
  return *(u16*)&h;
}
static __device__ __forceinline__ float bf2f(u16 u) {
  __hip_bfloat16 h; *(u16*)&h = u;
  return __bfloat162float(h);
}

// ---------------------------------------------------------------------------
// Row-wise L2 normalize -> bf16 hi/lo split. Optional g, clip, c2 (sum of
// fp32-normalized squares, matching prior rounds' c2 semantics).
// ---------------------------------------------------------------------------
__global__ __launch_bounds__(256) void rownorm_split(
    const float* __restrict__ v, const float* __restrict__ g,
    u16* __restrict__ hi, u16* __restrict__ lo, float* __restrict__ c2,
    int ncols, int clip) {
  __shared__ float red[256];
  int row = blockIdx.x;
  const float* vr = v + (size_t)row * ncols;
  float s = 0.f;
  for (int j = threadIdx.x; j < ncols; j += 256) { float x = vr[j]; s += x * x; }
  red[threadIdx.x] = s;
  __syncthreads();
  for (int off = 128; off > 0; off >>= 1) {
    if (threadIdx.x < off) red[threadIdx.x] += red[threadIdx.x + off];
    __syncthreads();
  }
  float norm = sqrtf(red[0]);
  if (clip) norm = fmaxf(norm, 1e-12f);
  float scale = (g ? g[row] : 1.0f) / norm;
  float s2 = 0.f;
  for (int j = threadIdx.x; j < ncols; j += 256) {
    float y = vr[j] * scale;
    u16 hh = f2bf(y);
    u16 ll = f2bf(y - bf2f(hh));
    hi[(size_t)row * ncols + j] = hh;
    lo[(size_t)row * ncols + j] = ll;
    s2 += y * y;
  }
  if (c2) {
    __syncthreads();
    red[threadIdx.x] = s2;
    __syncthreads();
    for (int off = 128; off > 0; off >>= 1) {
      if (threadIdx.x < off) red[threadIdx.x] += red[threadIdx.x + off];
      __syncthreads();
    }
    if (threadIdx.x == 0) c2[row] = red[0];
  }
}

// ---------------------------------------------------------------------------
// z [d][t] fp32 -> zth/ztl [t][d] bf16 hi/lo (LDS 64x64 tile transpose)
// ---------------------------------------------------------------------------
__global__ __launch_bounds__(256) void transpose_split_z(
    const float* __restrict__ z, u16* __restrict__ zth, u16* __restrict__ ztl) {
  __shared__ float tile[64][65];
  int t0 = blockIdx.x * 64, d0 = blockIdx.y * 64;
  int tl = threadIdx.x & 63, grp = threadIdx.x >> 6;
#pragma unroll
  for (int r = 0; r < 16; r++) {
    int d = grp * 16 + r;
    tile[d][tl] = z[(size_t)(d0 + d) * TDIM + t0 + tl];
  }
  __syncthreads();
#pragma unroll
  for (int r = 0; r < 16; r++) {
    int t = grp * 16 + r;
    float x = tile[tl][t];
    u16 h = f2bf(x);
    u16 l = f2bf(x - bf2f(h));
    zth[(size_t)(t0 + t) * DDIM + d0 + tl] = h;
    ztl[(size_t)(t0 + t) * DDIM + d0 + tl] = l;
  }
}

// ---------------------------------------------------------------------------
// Unified split-bf16 MFMA GEMM + bias: C[m][t] = A[m]·B[t] + bias[m]
// A = ah/al [M][K] (k-minor), B = bh/bl [TDIM][K] (k-minor), C [M][TDIM].
// BM=BN=128, c-chunks of 32, XOR-swizzled LDS tiles (R6-verified), 3-term
// split-bf16 (hi*hi + lo*hi + hi*lo) for fp32-grade accuracy on MFMA.
// Used for both in_proj (K=1024) and out_proj (K=256).
// ---------------------------------------------------------------------------
__global__ __launch_bounds__(256) void gemm_mfma_bias(
    const u16* __restrict__ ah_g, const u16* __restrict__ al_g,
    const u16* __restrict__ bh_g, const u16* __restrict__ bl_g,
    const float* __restrict__ bias, float* __restrict__ C, int K) {
  __shared__ u16 Ah[128 * 32], Al[128 * 32];
  __shared__ u16 Bh[128 * 32], Bl[128 * 32];
  int tid = threadIdx.x;
  int n0 = blockIdx.x * 128;     // t
  int m0 = blockIdx.y * 128;     // output rows
  int lane = tid & 63, wid = tid >> 6;
  int wr = wid >> 1, wc = wid & 1;
  int q = lane >> 4, mm = lane & 15;
  int h = tid & 1;
  int sr = ((tid >> 1) ^ (h << 2)) & 127;
  int ssw = (sr ^ (sr >> 2)) & 3;
  int o0 = sr * 32 + ((((h << 1))     ^ ssw) << 3);
  int o1 = sr * 32 + ((((h << 1) | 1) ^ ssw) << 3);
  int gcol = h * 16;
  int sm = (mm ^ (mm >> 2)) & 3;
  int cq = (q ^ sm) << 3;

  const floatx4 z4 = {0.f, 0.f, 0.f, 0.f};
  floatx4 acc[4][4];
#pragma unroll
  for (int i = 0; i < 4; i++)
#pragma unroll
    for (int j = 0; j < 4; j++) acc[i][j] = z4;

  for (int c0 = 0; c0 < K; c0 += 32) {
    const size_t ga = (size_t)(m0 + sr) * K + c0 + gcol;
    const size_t gb = (size_t)(n0 + sr) * K + c0 + gcol;
    us8 a_h0 = *(const us8*)&ah_g[ga];
    us8 a_h1 = *(const us8*)&ah_g[ga + 8];
    us8 a_l0 = *(const us8*)&al_g[ga];
    us8 a_l1 = *(const us8*)&al_g[ga + 8];
    us8 b_h0 = *(const us8*)&bh_g[gb];
    us8 b_h1 = *(const us8*)&bh_g[gb + 8];
    us8 b_l0 = *(const us8*)&bl_g[gb];
    us8 b_l1 = *(const us8*)&bl_g[gb + 8];
    __syncthreads();
    *(us8*)&Ah[o0] = a_h0; *(us8*)&Ah[o1] = a_h1;
    *(us8*)&Al[o0] = a_l0; *(us8*)&Al[o1] = a_l1;
    *(us8*)&Bh[o0] = b_h0; *(us8*)&Bh[o1] = b_h1;
    *(us8*)&Bl[o0] = b_l0; *(us8*)&Bl[o1] = b_l1;
    __syncthreads();

    bf16x8 fa[4], fb[4];
#pragma unroll
    for (int i = 0; i < 4; i++)
      fa[i] = *(const bf16x8*)&Ah[(wr * 64 + i * 16 + mm) * 32 + cq];
#pragma unroll
    for (int j = 0; j < 4; j++)
      fb[j] = *(const bf16x8*)&Bh[(wc * 64 + j * 16 + mm) * 32 + cq];
#pragma unroll
    for (int i = 0; i < 4; i++)
#pragma unroll
      for (int j = 0; j < 4; j++)
        acc[i][j] = __builtin_amdgcn_mfma_f32_16x16x32_bf16(fa[i], fb[j], acc[i][j], 0, 0, 0);
#pragma unroll
    for (int i = 0; i < 4; i++) {
      bf16x8 fl = *(const bf16x8*)&Al[(wr * 64 + i * 16 + mm) * 32 + cq];
#pragma unroll
      for (int j = 0; j < 4; j++)
        acc[i][j] = __builtin_amdgcn_mfma_f32_16x16x32_bf16(fl, fb[j], acc[i][j], 0, 0, 0);
    }
#pragma unroll
    for (int j = 0; j < 4; j++) {
      bf16x8 fl = *(const bf16x8*)&Bl[(wc * 64 + j * 16 + mm) * 32 + cq];
#pragma unroll
      for (int i = 0; i < 4; i++)
        acc[i][j] = __builtin_amdgcn_mfma_f32_16x16x32_bf16(fa[i], fl, acc[i][j], 0, 0, 0);
    }
  }

  // epilogue: row = wr*64+i*16+q*4+r, col = wc*64+j*16+mm
#pragma unroll
  for (int i = 0; i < 4; i++) {
#pragma unroll
    for (int r = 0; r < 4; r++) {
      int m_loc = wr * 64 + i * 16 + q * 4 + r;
      float bb = bias[m0 + m_loc];
      float* crow = &C[(size_t)(m0 + m_loc) * TDIM + n0 + wc * 64 + mm];
#pragma unroll
      for (int j = 0; j < 4; j++) crow[j * 16] = acc[i][j][r] + bb;
    }
  }
}

// ---------------------------------------------------------------------------
// finish_ze: fused column-norm + transpose + bf16 split.
// Reads z_e [256][T], computes inv[t] = 1/clip(||z_e[:,t]||), writes
// eth/etl [t][c] = split(z_e[c][t] * inv[t]). LDS tile 256x67 (67 coprime
// with 32 -> conflict-free column reads).
// ---------------------------------------------------------------------------
__global__ __launch_bounds__(256) void finish_ze(
    const float* __restrict__ ze, u16* __restrict__ eth, u16* __restrict__ etl) {
  __shared__ float tile[256][67];
  __shared__ float red[4][64];
  __shared__ float invs[64];
  int t0 = blockIdx.x * 64;
  int tl = threadIdx.x & 63, grp = threadIdx.x >> 6;
  float s = 0.f;
  for (int c = grp * 64; c < grp * 64 + 64; c++) {
    float v = ze[(size_t)c * TDIM + t0 + tl];
    tile[c][tl] = v;
    s += v * v;
  }
  red[grp][tl] = s;
  __syncthreads();
  if (grp == 0) {
    float tot = red[0][tl] + red[1][tl] + red[2][tl] + red[3][tl];
    invs[tl] = 1.0f / fmaxf(sqrtf(tot), 1e-12f);
  }
  __syncthreads();
#pragma unroll
  for (int r = 0; r < 16; r++) {
    int t = grp * 16 + r;
    float iv = invs[t];
#pragma unroll
    for (int cc = 0; cc < 4; cc++) {
      int cd = cc * 64 + tl;
      float x = tile[cd][t] * iv;
      u16 hh = f2bf(x);
      u16 ll = f2bf(x - bf2f(hh));
      eth[(size_t)(t0 + t) * CDIM + cd] = hh;
      etl[(size_t)(t0 + t) * CDIM + cd] = ll;
    }
  }
}

// ---------------------------------------------------------------------------
// dist + argmin via split-bf16 MFMA — UNCHANGED from R6 (verified).
// ---------------------------------------------------------------------------
__global__ __launch_bounds__(256) void dist_mfma(
    const u16* __restrict__ eth, const u16* __restrict__ etl,
    const u16* __restrict__ cbh, const u16* __restrict__ cbl,
    const float* __restrict__ c2, float* __restrict__ pv, int* __restrict__ pi) {
  __shared__ u16 Ah[128 * 32], Al[128 * 32];
  __shared__ u16 Bh[128 * 32], Bl[128 * 32];
  __shared__ float mv[2][128];
  __shared__ int   mi[2][128];
  int tid = threadIdx.x;
  int t0 = blockIdx.x * 128;
  int kbeg = blockIdx.y * (KDIM / KSPLIT);
  int lane = tid & 63, wid = tid >> 6;
  int wr = wid >> 1, wc = wid & 1;
  int q = lane >> 4, mm = lane & 15;
  int h = tid & 1;
  int sr = ((tid >> 1) ^ (h << 2)) & 127;
  int ssw = (sr ^ (sr >> 2)) & 3;
  int o0 = sr * 32 + ((((h << 1))     ^ ssw) << 3);
  int o1 = sr * 32 + ((((h << 1) | 1) ^ ssw) << 3);
  int gcol = h * 16;
  int sm = (mm ^ (mm >> 2)) & 3;
  int cq = (q ^ sm) << 3;

  float rbv[4]; int rbi[4];
#pragma unroll
  for (int i = 0; i < 4; i++) { rbv[i] = INFINITY; rbi[i] = 0x7fffffff; }

  const floatx4 z4 = {0.f, 0.f, 0.f, 0.f};
  for (int ktile = 0; ktile < KDIM / KSPLIT; ktile += 128) {
    int k0 = kbeg + ktile;
    floatx4 acc[4][4];
#pragma unroll
    for (int i = 0; i < 4; i++)
#pragma unroll
      for (int j = 0; j < 4; j++) acc[i][j] = z4;

    for (int c0 = 0; c0 < CDIM; c0 += 32) {
      const size_t ga = (size_t)(k0 + sr) * CDIM + c0 + gcol;
      const size_t gb = (size_t)(t0 + sr) * CDIM + c0 + gcol;
      us8 a_h0 = *(const us8*)&cbh[ga];
      us8 a_h1 = *(const us8*)&cbh[ga + 8];
      us8 a_l0 = *(const us8*)&cbl[ga];
      us8 a_l1 = *(const us8*)&cbl[ga + 8];
      us8 b_h0 = *(const us8*)&eth[gb];
      us8 b_h1 = *(const us8*)&eth[gb + 8];
      us8 b_l0 = *(const us8*)&etl[gb];
      us8 b_l1 = *(const us8*)&etl[gb + 8];
      __syncthreads();
      *(us8*)&Ah[o0] = a_h0; *(us8*)&Ah[o1] = a_h1;
      *(us8*)&Al[o0] = a_l0; *(us8*)&Al[o1] = a_l1;
      *(us8*)&Bh[o0] = b_h0; *(us8*)&Bh[o1] = b_h1;
      *(us8*)&Bl[o0] = b_l0; *(us8*)&Bl[o1] = b_l1;
      __syncthreads();

      bf16x8 fa[4], fb[4];
#pragma unroll
      for (int i = 0; i < 4; i++)
        fa[i] = *(const bf16x8*)&Ah[(wr * 64 + i * 16 + mm) * 32 + cq];
#pragma unroll
      for (int j = 0; j < 4; j++)
        fb[j] = *(const bf16x8*)&Bh[(wc * 64 + j * 16 + mm) * 32 + cq];
#pragma unroll
      for (int i = 0; i < 4; i++)
#pragma unroll
        for (int j = 0; j < 4; j++)
          acc[i][j] = __builtin_amdgcn_mfma_f32_16x16x32_bf16(fa[i], fb[j], acc[i][j], 0, 0, 0);
#pragma unroll
      for (int i = 0; i < 4; i++) {
        bf16x8 fl = *(const bf16x8*)&Al[(wr * 64 + i * 16 + mm) * 32 + cq];
#pragma unroll
        for (int j = 0; j < 4; j++)
          acc[i][j] = __builtin_amdgcn_mfma_f32_16x16x32_bf16(fl, fb[j], acc[i][j], 0, 0, 0);
      }
#pragma unroll
      for (int j = 0; j < 4; j++) {
        bf16x8 fl = *(const bf16x8*)&Bl[(wc * 64 + j * 16 + mm) * 32 + cq];
#pragma unroll
        for (int i = 0; i < 4; i++)
          acc[i][j] = __builtin_amdgcn_mfma_f32_16x16x32_bf16(fa[i], fl, acc[i][j], 0, 0, 0);
      }
    }

#pragma unroll
    for (int i = 0; i < 4; i++) {
#pragma unroll
      for (int r = 0; r < 4; r++) {
        int klocal = wr * 64 + i * 16 + q * 4 + r;
        float c2v = c2[k0 + klocal];
        int kg = k0 + klocal;
#pragma unroll
        for (int j = 0; j < 4; j++) {
          float s = c2v - 2.0f * acc[i][j][r];
          if (s < rbv[j]) { rbv[j] = s; rbi[j] = kg; }
        }
      }
    }
  }

#pragma unroll
  for (int j = 0; j < 4; j++) {
    float v = rbv[j]; int ii = rbi[j];
    float ov = __shfl_xor(v, 16, 64); int oi = __shfl_xor(ii, 16, 64);
    if (ov < v || (ov == v && oi < ii)) { v = ov; ii = oi; }
    ov = __shfl_xor(v, 32, 64); oi = __shfl_xor(ii, 32, 64);
    if (ov < v || (ov == v && oi < ii)) { v = ov; ii = oi; }
    rbv[j] = v; rbi[j] = ii;
  }
  if (q == 0) {
#pragma unroll
    for (int j = 0; j < 4; j++) {
      mv[wr][wc * 64 + j * 16 + mm] = rbv[j];
      mi[wr][wc * 64 + j * 16 + mm] = rbi[j];
    }
  }
  __syncthreads();
  if (tid < 128) {
    float v0 = mv[0][tid]; int i0 = mi[0][tid];
    float v1 = mv[1][tid]; int i1 = mi[1][tid];
    if (v1 < v0 || (v1 == v0 && i1 < i0)) { v0 = v1; i0 = i1; }
    pv[(size_t)blockIdx.y * TDIM + t0 + tid] = v0;
    pi[(size_t)blockIdx.y * TDIM + t0 + tid] = i0;
  }
}

// ---------------------------------------------------------------------------
// merge k-splits; emit int idx (for gather) and float idx (output 1)
// ---------------------------------------------------------------------------
__global__ __launch_bounds__(256) void merge_argmin(
    const float* __restrict__ pv, const int* __restrict__ pi,
    int* __restrict__ idx, float* __restrict__ idxf) {
  int t = blockIdx.x * 256 + threadIdx.x;
  float bv = INFINITY; int bi = 0x7fffffff;
  for (int s = 0; s < KSPLIT; s++) {
    float v = pv[(size_t)s * TDIM + t];
    int ii = pi[(size_t)s * TDIM + t];
    if (v < bv || (v == bv && ii < bi)) { bv = v; bi = ii; }
  }
  idx[t] = bi;
  idxf[t] = (float)bi;
}

// ---------------------------------------------------------------------------
// gather: zqT[t][c] = split(cb[idx[t]][c]).
// (ref computes zq = ze + (cb - ze) in fp32, which differs from cb by ~1 ulp
//  of ze — negligible vs the bf16-level output absmax; lets us drop the
//  ze dependency entirely.)
// ---------------------------------------------------------------------------
__global__ __launch_bounds__(256) void gather_split(
    const int* __restrict__ idx, const float* __restrict__ cb,
    u16* __restrict__ zqh, u16* __restrict__ zql) {
  int t = blockIdx.x;
  int c = threadIdx.x;
  int k = idx[t];
  float x = cb[(size_t)k * CDIM + c];
  u16 hh = f2bf(x);
  u16 ll = f2bf(x - bf2f(hh));
  zqh[(size_t)t * CDIM + c] = hh;
  zql[(size_t)t * CDIM + c] = ll;
}

extern "C" void kernel_launch(void* const* d_in, const int* in_sizes, int n_in,
                              void* d_out, int out_size, void* d_ws, size_t ws_size,
                              hipStream_t stream) {
  const float* z     = (const float*)d_in[0];
  const float* in_v  = (const float*)d_in[1];
  const float* in_g  = (const float*)d_in[2];
  const float* in_b  = (const float*)d_in[3];
  const float* out_v = (const float*)d_in[4];
  const float* out_g = (const float*)d_in[5];
  const float* out_b = (const float*)d_in[6];
  const float* cb    = (const float*)d_in[7];

  float* ws    = (float*)d_ws;
  u16*   winh  = (u16*)(ws + OFF_WINH);
  u16*   winl  = (u16*)(ws + OFF_WINL);
  u16*   wouth = (u16*)(ws + OFF_WOUTH);
  u16*   woutl = (u16*)(ws + OFF_WOUTL);
  u16*   cbh   = (u16*)(ws + OFF_CBH);
  u16*   cbl   = (u16*)(ws + OFF_CBL);
  float* c2    = ws + OFF_C2;
  u16*   zth   = (u16*)(ws + OFF_ZTH);
  u16*   ztl   = (u16*)(ws + OFF_ZTL);
  float* z_e   = ws + OFF_ZE;
  float* pv    = ws + OFF_PV;
  int*   pi    = (int*)(ws + OFF_PI);
  int*   idxw  = (int*)(ws + OFF_IDX);
  u16*   eth   = (u16*)(ws + OFF_ETH);   // aliases zth (dead after in_proj)
  u16*   etl   = (u16*)(ws + OFF_ETL);
  u16*   zqh   = eth;                    // aliases eth (dead after dist)
  u16*   zql   = etl;

  float* outp = (float*)d_out;                 // (1024 x 16384) fp32
  float* idxf = outp + (size_t)DDIM * TDIM;    // indices as float32

  // weight prep: all weights emitted directly as split-bf16
  rownorm_split<<<CDIM, 256, 0, stream>>>(in_v, in_g, winh, winl, nullptr, DDIM, 0);
  rownorm_split<<<DDIM, 256, 0, stream>>>(out_v, out_g, wouth, woutl, nullptr, CDIM, 0);
  rownorm_split<<<KDIM, 256, 0, stream>>>(cb, nullptr, cbh, cbl, c2, CDIM, 1);

  // z -> zT split (for in_proj B operand)
  transpose_split_z<<<dim3(TDIM / 64, DDIM / 64), 256, 0, stream>>>(z, zth, ztl);

  // z_e = W_in @ z + in_b  (split-bf16 MFMA, K=1024)
  gemm_mfma_bias<<<dim3(TDIM / 128, CDIM / 128), 256, 0, stream>>>(
      winh, winl, zth, ztl, in_b, z_e, DDIM);

  // fused colnorm + transpose + split -> eth/etl [t][c]
  finish_ze<<<TDIM / 64, 256, 0, stream>>>(z_e, eth, etl);

  // nearest-codebook argmin (k-split x8)
  dist_mfma<<<dim3(TDIM / 128, KSPLIT), 256, 0, stream>>>(eth, etl, cbh, cbl, c2, pv, pi);
  merge_argmin<<<TDIM / 256, 256, 0, stream>>>(pv, pi, idxw, idxf);

  // zq = cb[idx] -> split [t][c]
  gather_split<<<TDIM, 256, 0, stream>>>(idxw, cb, zqh, zql);

  // out = W_out @ z_q + out_b  (split-bf16 MFMA, K=256)
  gemm_mfma_bias<<<dim3(TDIM / 128, DDIM / 128), 256, 0, stream>>>(
      wouth, woutl, zqh, zql, out_b, outp, CDIM);
}

// Round 8
// 465.455 us; speedup vs baseline: 15.6526x; 1.0098x over previous
//
#include <hip/hip_runtime.h>
#include <hip/hip_bf16.h>
#include <math.h>

#define TDIM 16384
#define DDIM 1024
#define CDIM 256
#define KDIM 8192
#define KSPLIT 8

typedef unsigned short u16;
typedef __attribute__((ext_vector_type(8))) short bf16x8;
typedef __attribute__((ext_vector_type(8))) unsigned short us8;
typedef __attribute__((ext_vector_type(4))) float floatx4;

// ---- workspace layout (float offsets) ----
static const size_t OFF_WINH  = 0;                                     // 256x1024 u16
static const size_t OFF_WINL  = OFF_WINH  + (size_t)CDIM * DDIM / 2;
static const size_t OFF_WOUTH = OFF_WINL  + (size_t)CDIM * DDIM / 2;   // 1024x256 u16
static const size_t OFF_WOUTL = OFF_WOUTH + (size_t)DDIM * CDIM / 2;
static const size_t OFF_CBH   = OFF_WOUTL + (size_t)DDIM * CDIM / 2;   // 8192x256 u16
static const size_t OFF_CBL   = OFF_CBH   + (size_t)KDIM * CDIM / 2;
static const size_t OFF_C2    = OFF_CBL   + (size_t)KDIM * CDIM / 2;   // 8192 f32
static const size_t OFF_ZTH   = OFF_C2    + (size_t)KDIM;              // 16384x1024 u16 [t][d]
static const size_t OFF_ZTL   = OFF_ZTH   + (size_t)TDIM * DDIM / 2;
static const size_t OFF_ZE    = OFF_ZTL   + (size_t)TDIM * DDIM / 2;   // 256x16384 f32
static const size_t OFF_PV    = OFF_ZE    + (size_t)CDIM * TDIM;       // 8x16384 f32
static const size_t OFF_PI    = OFF_PV    + (size_t)KSPLIT * TDIM;     // 8x16384 i32
static const size_t OFF_IDX   = OFF_PI    + (size_t)KSPLIT * TDIM;     // 16384 i32
// eth/etl [t][c] alias ZTH (zth/ztl dead after in_proj gemm);
// zqh/zql alias the same region again (eth/etl dead after dist_mfma).
static const size_t OFF_ETH   = OFF_ZTH;
static const size_t OFF_ETL   = OFF_ZTH + (size_t)TDIM * CDIM / 2;

static __device__ __forceinline__ u16 f2bf(float x) {
  __hip_bfloat16 h = __float2bfloat16(x);
  return *(u16*)&h;
}
static __device__ __forceinline__ float bf2f(u16 u) {
  __hip_bfloat16 h; *(u16*)&h = u;
  return __bfloat162float(h);
}

// ---------------------------------------------------------------------------
// Row-wise L2 normalize -> bf16 hi/lo split. Optional g, clip, c2.
// ---------------------------------------------------------------------------
__global__ __launch_bounds__(256) void rownorm_split(
    const float* __restrict__ v, const float* __restrict__ g,
    u16* __restrict__ hi, u16* __restrict__ lo, float* __restrict__ c2,
    int ncols, int clip) {
  __shared__ float red[256];
  int row = blockIdx.x;
  const float* vr = v + (size_t)row * ncols;
  float s = 0.f;
  for (int j = threadIdx.x; j < ncols; j += 256) { float x = vr[j]; s += x * x; }
  red[threadIdx.x] = s;
  __syncthreads();
  for (int off = 128; off > 0; off >>= 1) {
    if (threadIdx.x < off) red[threadIdx.x] += red[threadIdx.x + off];
    __syncthreads();
  }
  float norm = sqrtf(red[0]);
  if (clip) norm = fmaxf(norm, 1e-12f);
  float scale = (g ? g[row] : 1.0f) / norm;
  float s2 = 0.f;
  for (int j = threadIdx.x; j < ncols; j += 256) {
    float y = vr[j] * scale;
    u16 hh = f2bf(y);
    u16 ll = f2bf(y - bf2f(hh));
    hi[(size_t)row * ncols + j] = hh;
    lo[(size_t)row * ncols + j] = ll;
    s2 += y * y;
  }
  if (c2) {
    __syncthreads();
    red[threadIdx.x] = s2;
    __syncthreads();
    for (int off = 128; off > 0; off >>= 1) {
      if (threadIdx.x < off) red[threadIdx.x] += red[threadIdx.x + off];
      __syncthreads();
    }
    if (threadIdx.x == 0) c2[row] = red[0];
  }
}

// ---------------------------------------------------------------------------
// z [d][t] fp32 -> zth/ztl [t][d] bf16 hi/lo (LDS 64x64 tile transpose)
// ---------------------------------------------------------------------------
__global__ __launch_bounds__(256) void transpose_split_z(
    const float* __restrict__ z, u16* __restrict__ zth, u16* __restrict__ ztl) {
  __shared__ float tile[64][65];
  int t0 = blockIdx.x * 64, d0 = blockIdx.y * 64;
  int tl = threadIdx.x & 63, grp = threadIdx.x >> 6;
#pragma unroll
  for (int r = 0; r < 16; r++) {
    int d = grp * 16 + r;
    tile[d][tl] = z[(size_t)(d0 + d) * TDIM + t0 + tl];
  }
  __syncthreads();
#pragma unroll
  for (int r = 0; r < 16; r++) {
    int t = grp * 16 + r;
    float x = tile[tl][t];
    u16 h = f2bf(x);
    u16 l = f2bf(x - bf2f(h));
    zth[(size_t)(t0 + t) * DDIM + d0 + tl] = h;
    ztl[(size_t)(t0 + t) * DDIM + d0 + tl] = l;
  }
}

// ---------------------------------------------------------------------------
// in_proj split-bf16 MFMA GEMM, BN=64: C[m][t] = A[m]·B[t] + bias[m]
// M=256 -> grid (TDIM/64, 2) = 512 blocks (2/CU vs 1/CU at BN=128).
// Wave tile 64m x 32t, acc[4][2] (32 acc regs -> lower unified VGPR+ACC
// pressure than BN=128's 64). Same c-chunk sequence + 3-term order as the
// BN=128 kernel -> per-element accumulation order identical -> z_e bit-equal.
// ---------------------------------------------------------------------------
__global__ __launch_bounds__(256) void gemm_mfma_in(
    const u16* __restrict__ ah_g, const u16* __restrict__ al_g,
    const u16* __restrict__ bh_g, const u16* __restrict__ bl_g,
    const float* __restrict__ bias, float* __restrict__ C, int K) {
  __shared__ u16 Ah[128 * 32], Al[128 * 32];
  __shared__ u16 Bh[64 * 32],  Bl[64 * 32];
  int tid = threadIdx.x;
  int n0 = blockIdx.x * 64;      // t
  int m0 = blockIdx.y * 128;     // output rows
  int lane = tid & 63, wid = tid >> 6;
  int wr = wid >> 1, wc = wid & 1;
  int q = lane >> 4, mm = lane & 15;
  int h = tid & 1;
  int sr = ((tid >> 1) ^ (h << 2)) & 127;
  int ssw = (sr ^ (sr >> 2)) & 3;
  int o0 = sr * 32 + ((((h << 1))     ^ ssw) << 3);
  int o1 = sr * 32 + ((((h << 1) | 1) ^ ssw) << 3);
  int gcol = h * 16;
  // B staging (64 rows): threads tid<128 cover 64 rows x 2 halves
  int sb = ((tid >> 1) ^ (h << 2)) & 63;
  int ssb = (sb ^ (sb >> 2)) & 3;
  int p0 = sb * 32 + ((((h << 1))     ^ ssb) << 3);
  int p1 = sb * 32 + ((((h << 1) | 1) ^ ssb) << 3);
  int sm = (mm ^ (mm >> 2)) & 3;
  int cq = (q ^ sm) << 3;

  const floatx4 z4 = {0.f, 0.f, 0.f, 0.f};
  floatx4 acc[4][2];
#pragma unroll
  for (int i = 0; i < 4; i++)
#pragma unroll
    for (int j = 0; j < 2; j++) acc[i][j] = z4;

  for (int c0 = 0; c0 < K; c0 += 32) {
    const size_t ga = (size_t)(m0 + sr) * K + c0 + gcol;
    us8 a_h0 = *(const us8*)&ah_g[ga];
    us8 a_h1 = *(const us8*)&ah_g[ga + 8];
    us8 a_l0 = *(const us8*)&al_g[ga];
    us8 a_l1 = *(const us8*)&al_g[ga + 8];
    us8 b_h0, b_h1, b_l0, b_l1;
    if (tid < 128) {
      const size_t gb = (size_t)(n0 + sb) * K + c0 + gcol;
      b_h0 = *(const us8*)&bh_g[gb];
      b_h1 = *(const us8*)&bh_g[gb + 8];
      b_l0 = *(const us8*)&bl_g[gb];
      b_l1 = *(const us8*)&bl_g[gb + 8];
    }
    __syncthreads();
    *(us8*)&Ah[o0] = a_h0; *(us8*)&Ah[o1] = a_h1;
    *(us8*)&Al[o0] = a_l0; *(us8*)&Al[o1] = a_l1;
    if (tid < 128) {
      *(us8*)&Bh[p0] = b_h0; *(us8*)&Bh[p1] = b_h1;
      *(us8*)&Bl[p0] = b_l0; *(us8*)&Bl[p1] = b_l1;
    }
    __syncthreads();

    bf16x8 fa[4], fb[2];
#pragma unroll
    for (int i = 0; i < 4; i++)
      fa[i] = *(const bf16x8*)&Ah[(wr * 64 + i * 16 + mm) * 32 + cq];
#pragma unroll
    for (int j = 0; j < 2; j++)
      fb[j] = *(const bf16x8*)&Bh[(wc * 32 + j * 16 + mm) * 32 + cq];
#pragma unroll
    for (int i = 0; i < 4; i++)
#pragma unroll
      for (int j = 0; j < 2; j++)
        acc[i][j] = __builtin_amdgcn_mfma_f32_16x16x32_bf16(fa[i], fb[j], acc[i][j], 0, 0, 0);
#pragma unroll
    for (int i = 0; i < 4; i++) {
      bf16x8 fl = *(const bf16x8*)&Al[(wr * 64 + i * 16 + mm) * 32 + cq];
#pragma unroll
      for (int j = 0; j < 2; j++)
        acc[i][j] = __builtin_amdgcn_mfma_f32_16x16x32_bf16(fl, fb[j], acc[i][j], 0, 0, 0);
    }
#pragma unroll
    for (int j = 0; j < 2; j++) {
      bf16x8 fl = *(const bf16x8*)&Bl[(wc * 32 + j * 16 + mm) * 32 + cq];
#pragma unroll
      for (int i = 0; i < 4; i++)
        acc[i][j] = __builtin_amdgcn_mfma_f32_16x16x32_bf16(fa[i], fl, acc[i][j], 0, 0, 0);
    }
  }

#pragma unroll
  for (int i = 0; i < 4; i++) {
#pragma unroll
    for (int r = 0; r < 4; r++) {
      int m_loc = wr * 64 + i * 16 + q * 4 + r;
      float bb = bias[m0 + m_loc];
      float* crow = &C[(size_t)(m0 + m_loc) * TDIM + n0 + wc * 32 + mm];
#pragma unroll
      for (int j = 0; j < 2; j++) crow[j * 16] = acc[i][j][r] + bb;
    }
  }
}

// ---------------------------------------------------------------------------
// out_proj split-bf16 MFMA GEMM + bias, BN=128 (R6/R7-verified).
// ---------------------------------------------------------------------------
__global__ __launch_bounds__(256) void gemm_mfma_bias(
    const u16* __restrict__ ah_g, const u16* __restrict__ al_g,
    const u16* __restrict__ bh_g, const u16* __restrict__ bl_g,
    const float* __restrict__ bias, float* __restrict__ C, int K) {
  __shared__ u16 Ah[128 * 32], Al[128 * 32];
  __shared__ u16 Bh[128 * 32], Bl[128 * 32];
  int tid = threadIdx.x;
  int n0 = blockIdx.x * 128;
  int m0 = blockIdx.y * 128;
  int lane = tid & 63, wid = tid >> 6;
  int wr = wid >> 1, wc = wid & 1;
  int q = lane >> 4, mm = lane & 15;
  int h = tid & 1;
  int sr = ((tid >> 1) ^ (h << 2)) & 127;
  int ssw = (sr ^ (sr >> 2)) & 3;
  int o0 = sr * 32 + ((((h << 1))     ^ ssw) << 3);
  int o1 = sr * 32 + ((((h << 1) | 1) ^ ssw) << 3);
  int gcol = h * 16;
  int sm = (mm ^ (mm >> 2)) & 3;
  int cq = (q ^ sm) << 3;

  const floatx4 z4 = {0.f, 0.f, 0.f, 0.f};
  floatx4 acc[4][4];
#pragma unroll
  for (int i = 0; i < 4; i++)
#pragma unroll
    for (int j = 0; j < 4; j++) acc[i][j] = z4;

  for (int c0 = 0; c0 < K; c0 += 32) {
    const size_t ga = (size_t)(m0 + sr) * K + c0 + gcol;
    const size_t gb = (size_t)(n0 + sr) * K + c0 + gcol;
    us8 a_h0 = *(const us8*)&ah_g[ga];
    us8 a_h1 = *(const us8*)&ah_g[ga + 8];
    us8 a_l0 = *(const us8*)&al_g[ga];
    us8 a_l1 = *(const us8*)&al_g[ga + 8];
    us8 b_h0 = *(const us8*)&bh_g[gb];
    us8 b_h1 = *(const us8*)&bh_g[gb + 8];
    us8 b_l0 = *(const us8*)&bl_g[gb];
    us8 b_l1 = *(const us8*)&bl_g[gb + 8];
    __syncthreads();
    *(us8*)&Ah[o0] = a_h0; *(us8*)&Ah[o1] = a_h1;
    *(us8*)&Al[o0] = a_l0; *(us8*)&Al[o1] = a_l1;
    *(us8*)&Bh[o0] = b_h0; *(us8*)&Bh[o1] = b_h1;
    *(us8*)&Bl[o0] = b_l0; *(us8*)&Bl[o1] = b_l1;
    __syncthreads();

    bf16x8 fa[4], fb[4];
#pragma unroll
    for (int i = 0; i < 4; i++)
      fa[i] = *(const bf16x8*)&Ah[(wr * 64 + i * 16 + mm) * 32 + cq];
#pragma unroll
    for (int j = 0; j < 4; j++)
      fb[j] = *(const bf16x8*)&Bh[(wc * 64 + j * 16 + mm) * 32 + cq];
#pragma unroll
    for (int i = 0; i < 4; i++)
#pragma unroll
      for (int j = 0; j < 4; j++)
        acc[i][j] = __builtin_amdgcn_mfma_f32_16x16x32_bf16(fa[i], fb[j], acc[i][j], 0, 0, 0);
#pragma unroll
    for (int i = 0; i < 4; i++) {
      bf16x8 fl = *(const bf16x8*)&Al[(wr * 64 + i * 16 + mm) * 32 + cq];
#pragma unroll
      for (int j = 0; j < 4; j++)
        acc[i][j] = __builtin_amdgcn_mfma_f32_16x16x32_bf16(fl, fb[j], acc[i][j], 0, 0, 0);
    }
#pragma unroll
    for (int j = 0; j < 4; j++) {
      bf16x8 fl = *(const bf16x8*)&Bl[(wc * 64 + j * 16 + mm) * 32 + cq];
#pragma unroll
      for (int i = 0; i < 4; i++)
        acc[i][j] = __builtin_amdgcn_mfma_f32_16x16x32_bf16(fa[i], fl, acc[i][j], 0, 0, 0);
    }
  }

#pragma unroll
  for (int i = 0; i < 4; i++) {
#pragma unroll
    for (int r = 0; r < 4; r++) {
      int m_loc = wr * 64 + i * 16 + q * 4 + r;
      float bb = bias[m0 + m_loc];
      float* crow = &C[(size_t)(m0 + m_loc) * TDIM + n0 + wc * 64 + mm];
#pragma unroll
      for (int j = 0; j < 4; j++) crow[j * 16] = acc[i][j][r] + bb;
    }
  }
}

// ---------------------------------------------------------------------------
// finish_ze: fused column-norm + transpose + bf16 split, 32-t tiles.
// LDS 256x33 f32 (~34 KB) -> 4 blocks/CU residency; grid 512.
// ---------------------------------------------------------------------------
__global__ __launch_bounds__(256) void finish_ze(
    const float* __restrict__ ze, u16* __restrict__ eth, u16* __restrict__ etl) {
  __shared__ float tile[256][33];
  __shared__ float red[8][32];
  __shared__ float invs[32];
  int t0 = blockIdx.x * 32;
  int tl = threadIdx.x & 31, grp = threadIdx.x >> 5;
  float s = 0.f;
  for (int c = grp * 32; c < grp * 32 + 32; c++) {
    float v = ze[(size_t)c * TDIM + t0 + tl];
    tile[c][tl] = v;
    s += v * v;
  }
  red[grp][tl] = s;
  __syncthreads();
  if (grp == 0) {
    float tot = 0.f;
#pragma unroll
    for (int gg = 0; gg < 8; gg++) tot += red[gg][tl];
    invs[tl] = 1.0f / fmaxf(sqrtf(tot), 1e-12f);
  }
  __syncthreads();
#pragma unroll
  for (int r = 0; r < 4; r++) {
    int t = grp * 4 + r;
    float iv = invs[t];
#pragma unroll
    for (int cc = 0; cc < 8; cc++) {
      int cd = cc * 32 + tl;
      float x = tile[cd][t] * iv;
      u16 hh = f2bf(x);
      u16 ll = f2bf(x - bf2f(hh));
      eth[(size_t)(t0 + t) * CDIM + cd] = hh;
      etl[(size_t)(t0 + t) * CDIM + cd] = ll;
    }
  }
}

// ---------------------------------------------------------------------------
// dist + argmin via split-bf16 MFMA — UNCHANGED from R6/R7 (verified).
// ---------------------------------------------------------------------------
__global__ __launch_bounds__(256) void dist_mfma(
    const u16* __restrict__ eth, const u16* __restrict__ etl,
    const u16* __restrict__ cbh, const u16* __restrict__ cbl,
    const float* __restrict__ c2, float* __restrict__ pv, int* __restrict__ pi) {
  __shared__ u16 Ah[128 * 32], Al[128 * 32];
  __shared__ u16 Bh[128 * 32], Bl[128 * 32];
  __shared__ float mv[2][128];
  __shared__ int   mi[2][128];
  int tid = threadIdx.x;
  int t0 = blockIdx.x * 128;
  int kbeg = blockIdx.y * (KDIM / KSPLIT);
  int lane = tid & 63, wid = tid >> 6;
  int wr = wid >> 1, wc = wid & 1;
  int q = lane >> 4, mm = lane & 15;
  int h = tid & 1;
  int sr = ((tid >> 1) ^ (h << 2)) & 127;
  int ssw = (sr ^ (sr >> 2)) & 3;
  int o0 = sr * 32 + ((((h << 1))     ^ ssw) << 3);
  int o1 = sr * 32 + ((((h << 1) | 1) ^ ssw) << 3);
  int gcol = h * 16;
  int sm = (mm ^ (mm >> 2)) & 3;
  int cq = (q ^ sm) << 3;

  float rbv[4]; int rbi[4];
#pragma unroll
  for (int i = 0; i < 4; i++) { rbv[i] = INFINITY; rbi[i] = 0x7fffffff; }

  const floatx4 z4 = {0.f, 0.f, 0.f, 0.f};
  for (int ktile = 0; ktile < KDIM / KSPLIT; ktile += 128) {
    int k0 = kbeg + ktile;
    floatx4 acc[4][4];
#pragma unroll
    for (int i = 0; i < 4; i++)
#pragma unroll
      for (int j = 0; j < 4; j++) acc[i][j] = z4;

    for (int c0 = 0; c0 < CDIM; c0 += 32) {
      const size_t ga = (size_t)(k0 + sr) * CDIM + c0 + gcol;
      const size_t gb = (size_t)(t0 + sr) * CDIM + c0 + gcol;
      us8 a_h0 = *(const us8*)&cbh[ga];
      us8 a_h1 = *(const us8*)&cbh[ga + 8];
      us8 a_l0 = *(const us8*)&cbl[ga];
      us8 a_l1 = *(const us8*)&cbl[ga + 8];
      us8 b_h0 = *(const us8*)&eth[gb];
      us8 b_h1 = *(const us8*)&eth[gb + 8];
      us8 b_l0 = *(const us8*)&etl[gb];
      us8 b_l1 = *(const us8*)&etl[gb + 8];
      __syncthreads();
      *(us8*)&Ah[o0] = a_h0; *(us8*)&Ah[o1] = a_h1;
      *(us8*)&Al[o0] = a_l0; *(us8*)&Al[o1] = a_l1;
      *(us8*)&Bh[o0] = b_h0; *(us8*)&Bh[o1] = b_h1;
      *(us8*)&Bl[o0] = b_l0; *(us8*)&Bl[o1] = b_l1;
      __syncthreads();

      bf16x8 fa[4], fb[4];
#pragma unroll
      for (int i = 0; i < 4; i++)
        fa[i] = *(const bf16x8*)&Ah[(wr * 64 + i * 16 + mm) * 32 + cq];
#pragma unroll
      for (int j = 0; j < 4; j++)
        fb[j] = *(const bf16x8*)&Bh[(wc * 64 + j * 16 + mm) * 32 + cq];
#pragma unroll
      for (int i = 0; i < 4; i++)
#pragma unroll
        for (int j = 0; j < 4; j++)
          acc[i][j] = __builtin_amdgcn_mfma_f32_16x16x32_bf16(fa[i], fb[j], acc[i][j], 0, 0, 0);
#pragma unroll
      for (int i = 0; i < 4; i++) {
        bf16x8 fl = *(const bf16x8*)&Al[(wr * 64 + i * 16 + mm) * 32 + cq];
#pragma unroll
        for (int j = 0; j < 4; j++)
          acc[i][j] = __builtin_amdgcn_mfma_f32_16x16x32_bf16(fl, fb[j], acc[i][j], 0, 0, 0);
      }
#pragma unroll
      for (int j = 0; j < 4; j++) {
        bf16x8 fl = *(const bf16x8*)&Bl[(wc * 64 + j * 16 + mm) * 32 + cq];
#pragma unroll
        for (int i = 0; i < 4; i++)
          acc[i][j] = __builtin_amdgcn_mfma_f32_16x16x32_bf16(fa[i], fl, acc[i][j], 0, 0, 0);
      }
    }

#pragma unroll
    for (int i = 0; i < 4; i++) {
#pragma unroll
      for (int r = 0; r < 4; r++) {
        int klocal = wr * 64 + i * 16 + q * 4 + r;
        float c2v = c2[k0 + klocal];
        int kg = k0 + klocal;
#pragma unroll
        for (int j = 0; j < 4; j++) {
          float s = c2v - 2.0f * acc[i][j][r];
          if (s < rbv[j]) { rbv[j] = s; rbi[j] = kg; }
        }
      }
    }
  }

#pragma unroll
  for (int j = 0; j < 4; j++) {
    float v = rbv[j]; int ii = rbi[j];
    float ov = __shfl_xor(v, 16, 64); int oi = __shfl_xor(ii, 16, 64);
    if (ov < v || (ov == v && oi < ii)) { v = ov; ii = oi; }
    ov = __shfl_xor(v, 32, 64); oi = __shfl_xor(ii, 32, 64);
    if (ov < v || (ov == v && oi < ii)) { v = ov; ii = oi; }
    rbv[j] = v; rbi[j] = ii;
  }
  if (q == 0) {
#pragma unroll
    for (int j = 0; j < 4; j++) {
      mv[wr][wc * 64 + j * 16 + mm] = rbv[j];
      mi[wr][wc * 64 + j * 16 + mm] = rbi[j];
    }
  }
  __syncthreads();
  if (tid < 128) {
    float v0 = mv[0][tid]; int i0 = mi[0][tid];
    float v1 = mv[1][tid]; int i1 = mi[1][tid];
    if (v1 < v0 || (v1 == v0 && i1 < i0)) { v0 = v1; i0 = i1; }
    pv[(size_t)blockIdx.y * TDIM + t0 + tid] = v0;
    pi[(size_t)blockIdx.y * TDIM + t0 + tid] = i0;
  }
}

// ---------------------------------------------------------------------------
// merge k-splits; emit int idx (for gather) and float idx (output 1)
// ---------------------------------------------------------------------------
__global__ __launch_bounds__(256) void merge_argmin(
    const float* __restrict__ pv, const int* __restrict__ pi,
    int* __restrict__ idx, float* __restrict__ idxf) {
  int t = blockIdx.x * 256 + threadIdx.x;
  float bv = INFINITY; int bi = 0x7fffffff;
  for (int s = 0; s < KSPLIT; s++) {
    float v = pv[(size_t)s * TDIM + t];
    int ii = pi[(size_t)s * TDIM + t];
    if (v < bv || (v == bv && ii < bi)) { bv = v; bi = ii; }
  }
  idx[t] = bi;
  idxf[t] = (float)bi;
}

// ---------------------------------------------------------------------------
// gather: zqT[t][c] = split(cb[idx[t]][c]); 4 t per block, float4 loads.
// ---------------------------------------------------------------------------
__global__ __launch_bounds__(256) void gather_split(
    const int* __restrict__ idx, const float* __restrict__ cb,
    u16* __restrict__ zqh, u16* __restrict__ zql) {
  int t = blockIdx.x * 4 + (threadIdx.x >> 6);
  int c4 = (threadIdx.x & 63) * 4;
  int k = idx[t];
  float4 x = *(const float4*)&cb[(size_t)k * CDIM + c4];
  u16 h0 = f2bf(x.x), h1 = f2bf(x.y), h2 = f2bf(x.z), h3 = f2bf(x.w);
  u16 l0 = f2bf(x.x - bf2f(h0)), l1 = f2bf(x.y - bf2f(h1));
  u16 l2 = f2bf(x.z - bf2f(h2)), l3 = f2bf(x.w - bf2f(h3));
  ushort4 hv = {h0, h1, h2, h3}, lv = {l0, l1, l2, l3};
  *(ushort4*)&zqh[(size_t)t * CDIM + c4] = hv;
  *(ushort4*)&zql[(size_t)t * CDIM + c4] = lv;
}

extern "C" void kernel_launch(void* const* d_in, const int* in_sizes, int n_in,
                              void* d_out, int out_size, void* d_ws, size_t ws_size,
                              hipStream_t stream) {
  const float* z     = (const float*)d_in[0];
  const float* in_v  = (const float*)d_in[1];
  const float* in_g  = (const float*)d_in[2];
  const float* in_b  = (const float*)d_in[3];
  const float* out_v = (const float*)d_in[4];
  const float* out_g = (const float*)d_in[5];
  const float* out_b = (const float*)d_in[6];
  const float* cb    = (const float*)d_in[7];

  float* ws    = (float*)d_ws;
  u16*   winh  = (u16*)(ws + OFF_WINH);
  u16*   winl  = (u16*)(ws + OFF_WINL);
  u16*   wouth = (u16*)(ws + OFF_WOUTH);
  u16*   woutl = (u16*)(ws + OFF_WOUTL);
  u16*   cbh   = (u16*)(ws + OFF_CBH);
  u16*   cbl   = (u16*)(ws + OFF_CBL);
  float* c2    = ws + OFF_C2;
  u16*   zth   = (u16*)(ws + OFF_ZTH);
  u16*   ztl   = (u16*)(ws + OFF_ZTL);
  float* z_e   = ws + OFF_ZE;
  float* pv    = ws + OFF_PV;
  int*   pi    = (int*)(ws + OFF_PI);
  int*   idxw  = (int*)(ws + OFF_IDX);
  u16*   eth   = (u16*)(ws + OFF_ETH);   // aliases zth (dead after in_proj)
  u16*   etl   = (u16*)(ws + OFF_ETL);
  u16*   zqh   = eth;                    // aliases eth (dead after dist)
  u16*   zql   = etl;

  float* outp = (float*)d_out;                 // (1024 x 16384) fp32
  float* idxf = outp + (size_t)DDIM * TDIM;    // indices as float32

  // weight prep: all weights emitted directly as split-bf16
  rownorm_split<<<CDIM, 256, 0, stream>>>(in_v, in_g, winh, winl, nullptr, DDIM, 0);
  rownorm_split<<<DDIM, 256, 0, stream>>>(out_v, out_g, wouth, woutl, nullptr, CDIM, 0);
  rownorm_split<<<KDIM, 256, 0, stream>>>(cb, nullptr, cbh, cbl, c2, CDIM, 1);

  // z -> zT split (for in_proj B operand)
  transpose_split_z<<<dim3(TDIM / 64, DDIM / 64), 256, 0, stream>>>(z, zth, ztl);

  // z_e = W_in @ z + in_b  (split-bf16 MFMA, BN=64, K=1024)
  gemm_mfma_in<<<dim3(TDIM / 64, CDIM / 128), 256, 0, stream>>>(
      winh, winl, zth, ztl, in_b, z_e, DDIM);

  // fused colnorm + transpose + split -> eth/etl [t][c]
  finish_ze<<<TDIM / 32, 256, 0, stream>>>(z_e, eth, etl);

  // nearest-codebook argmin (k-split x8)
  dist_mfma<<<dim3(TDIM / 128, KSPLIT), 256, 0, stream>>>(eth, etl, cbh, cbl, c2, pv, pi);
  merge_argmin<<<TDIM / 256, 256, 0, stream>>>(pv, pi, idxw, idxf);

  // zq = cb[idx] -> split [t][c]
  gather_split<<<TDIM / 4, 256, 0, stream>>>(idxw, cb, zqh, zql);

  // out = W_out @ z_q + out_b  (split-bf16 MFMA, K=256)
  gemm_mfma_bias<<<dim3(TDIM / 128, DDIM / 128), 256, 0, stream>>>(
      wouth, woutl, zqh, zql, out_b, outp, CDIM);
}